// Round 16
// baseline (324.789 us; speedup 1.0000x reference)
//
#include <hip/hip_runtime.h>
#include <hip/hip_bf16.h>

// Sizes (fixed by the problem)
#define NATOMS 131072
#define NBLK   8192
#define HDIM   256
#define NHEAD  8
#define TDIM   336   // 320 aug dims + 1 (ck_b . Q) + pad

typedef __attribute__((ext_vector_type(8))) short short8;
typedef __attribute__((ext_vector_type(4))) float floatx4;

__device__ __forceinline__ float bfu2f(unsigned short u) {
  unsigned int v = ((unsigned int)u) << 16;
  return __builtin_bit_cast(float, v);
}
__device__ __forceinline__ unsigned short f2bfu(float f) {
  unsigned int u = __builtin_bit_cast(unsigned int, f);
  u += 0x7fffu + ((u >> 16) & 1u);
  return (unsigned short)(u >> 16);
}
// packs bf16(a) into low 16, bf16(b) into high 16 (RNE)
__device__ __forceinline__ unsigned int cvt2(float a, float b) {
  unsigned int r;
  asm("v_cvt_pk_bf16_f32 %0, %1, %2" : "=v"(r) : "v"(a), "v"(b));
  return r;
}

// ---------------- prepA: fused independent preps.
// b in [0,9): k0_prep ; [9,265): kp1 ; [265,586): kp3 (-> CV1Tb bf16 transposed) ;
// [586,1611): kcast {W1t, W2t, geomT, W2mTb} ; [1611,1867): WvTb.
__global__ __launch_bounds__(352) void prepA(
    const float* __restrict__ seed, const float* __restrict__ Wq,
    const float* __restrict__ bq, const float* __restrict__ Wk,
    const float* __restrict__ bk, unsigned short* __restrict__ A_bfT,
    float* __restrict__ sb,
    const float* __restrict__ cq_w, const float* __restrict__ cq_b,
    const float* __restrict__ ck_w, const float* __restrict__ ck_b,
    float* __restrict__ M, float* __restrict__ vbias,
    const float* __restrict__ cv_w, const float* __restrict__ cv_b,
    const float* __restrict__ w1m, const float* __restrict__ b1m,
    unsigned short* __restrict__ CV1Tb, float* __restrict__ cb1,
    const float* __restrict__ fw1, const float* __restrict__ fw2,
    const float* __restrict__ w2m, const float* __restrict__ geom_w,
    unsigned short* __restrict__ W1t, unsigned short* __restrict__ W2t,
    unsigned short* __restrict__ W2mTb, unsigned short* __restrict__ geomT,
    const float* __restrict__ Wv, unsigned short* __restrict__ WvTb) {
  __shared__ float row[256];
  int t = threadIdx.x, b = blockIdx.x;
  if (b < 9) {
    // ---- k0: q = seed@Wq+bq ; A_bfT ; sb
    if (t < 256) {
      float acc = bq[t];
      for (int c = 0; c < 256; ++c) acc += seed[c] * Wq[c * 256 + t];
      row[t] = acc;
    }
    __syncthreads();
    const float scale = 0.17677669529663687f;  // 1/sqrt(32)
    if (b < 8) {
      if (t < 256) {
        int o = b * 256 + t;
        int c = o >> 3, h = o & 7;
        float a = 0.f;
        for (int d = 0; d < 32; ++d) a += Wk[c * 256 + h * 32 + d] * row[h * 32 + d];
        A_bfT[h * 256 + c] = f2bfu(a * scale);
      }
    } else {
      if (t < 8) {
        float a = 0.f;
        for (int d = 0; d < 32; ++d) a += bk[t * 32 + d] * row[t * 32 + d];
        sb[t] = a * scale;
      }
      if (t < 256)
        for (int idx = t; idx < 2048; idx += 256) A_bfT[2048 + idx] = 0;
    }
  } else if (b < 265) {
    // ---- kp1: M[i][c] = cq_w[i,:] . ckT[:,c]
    int i = b - 9;
    if (t < 256) row[t] = cq_w[i * 256 + t];
    __syncthreads();
    if (t < TDIM) {
      float a = 0.f;
      if (t < 320) { const float* w = ck_w + t * 256; for (int j = 0; j < 256; ++j) a += row[j] * w[j]; }
      else if (t == 320) { for (int j = 0; j < 256; ++j) a += row[j] * ck_b[j]; }
      M[i * TDIM + t] = a;
    }
    if (i == 0) {
      __syncthreads();
      if (t < 256) row[t] = cq_b[t];
      __syncthreads();
      if (t < TDIM) {
        float a = 0.f;
        if (t < 320) { const float* w = ck_w + t * 256; for (int j = 0; j < 256; ++j) a += row[j] * w[j]; }
        else if (t == 320) { for (int j = 0; j < 256; ++j) a += row[j] * ck_b[j]; }
        vbias[t] = a;
      }
    }
  } else if (b < 586) {
    // ---- kp3: CV1Tb[j][k] = bf16(cv_w[k,:] . w1m[:,j]) ; block 320: cb1 f32
    int k = b - 265;
    if (t < 256) row[t] = (k < 320) ? cv_w[k * 256 + t] : cv_b[t];
    __syncthreads();
    if (t < 256) {
      float a = 0.f;
      for (int i = 0; i < 256; ++i) a += row[i] * w1m[i * 256 + t];
      if (k < 320) CV1Tb[t * 320 + k] = f2bfu(a);
      else cb1[t] = a + b1m[t];
    }
  } else if (b < 1611) {
    // ---- kcast
    int bb = b - 586;
    if (bb < 512) {
      if (t < 256) W1t[bb * 256 + t] = f2bfu(fw1[t * 512 + bb]);
    } else if (bb < 768) {
      int n = bb - 512;
      if (t < 256)
        for (int m = 0; m < 2; ++m) {
          int k = t + 256 * m;
          W2t[n * 512 + k] = f2bfu(fw2[k * 256 + n]);
        }
    } else if (bb == 768) {
      if (t < 256)
        for (int idx = t; idx < 2048; idx += 256) {
          int q = idx >> 5, r = idx & 31;
          geomT[idx] = (r < 16) ? f2bfu(geom_w[r * 64 + q]) : (unsigned short)0;
        }
    } else {
      int n = bb - 769;
      if (t < 256) W2mTb[n * 256 + t] = f2bfu(w2m[t * 256 + n]);
    }
  } else {
    // ---- WvTb[j][c] = bf16(Wv[c][j])
    int j = b - 1611;
    if (t < 256) WvTb[j * 256 + t] = f2bfu(Wv[t * 256 + j]);
  }
}

// ---------------- Kp2: MMTb[c][p] = bf16(Wo[p,:] . M[:,c]) ; block 256: vb2[c] = bo.M[:,c] + vbias[c]
__global__ __launch_bounds__(352) void kp2(const float* __restrict__ Wo,
    const float* __restrict__ bo, const float* __restrict__ M,
    const float* __restrict__ vbias, unsigned short* __restrict__ MMTb,
    float* __restrict__ vb2) {
  __shared__ float row[256];
  int p = blockIdx.x, t = threadIdx.x;
  const float* src = (p < 256) ? (Wo + p * 256) : bo;
  if (t < 256) row[t] = src[t];
  __syncthreads();
  if (t < TDIM) {
    float a = 0.f;
    for (int i = 0; i < 256; ++i) a += row[i] * M[i * TDIM + t];
    if (p < 256) MMTb[t * 256 + p] = f2bfu(a);
    else vb2[t] = a + vbias[t];
  }
}

// ---------------- KGM3 v2: fused kgm + kg3, LDS diet -> 3 wgs/CU.
// xs pad cols [256..264) hold wsm; r2 union: ysb -> {rbfpb, rbflb, TbfT}.
// Phases: load -> cent -> S -> Y -> BP -> rbfl -> {rbfp, T} -> scores -> z.
__global__ __launch_bounds__(256) void kgm3(const float* __restrict__ x,
    const float* __restrict__ pos,
    const unsigned short* __restrict__ A_bfT, const float* __restrict__ sb,
    const unsigned short* __restrict__ WvTb, const float* __restrict__ bv,
    const unsigned short* __restrict__ MMTb, const float* __restrict__ vb2,
    const float* __restrict__ centers, const float* __restrict__ widths,
    const unsigned short* __restrict__ geomT, const float* __restrict__ geom_b,
    float* __restrict__ z_f) {
  __shared__ unsigned short xs[64][264];            // cols 256..263 = wsm[row][0..7]
  __shared__ __align__(16) char r2[16896];          // ysb -> {rbfpb, rbflb, TbfT}
  unsigned short (*ysb)[8][264] = (unsigned short(*)[8][264])r2;          // 16896 B
  unsigned short (*rbfpb)[72] = (unsigned short(*)[72])r2;                // 9216 B
  unsigned short (*rbflb)[32] = (unsigned short(*)[32])(r2 + 9216);       // 4096 B
  unsigned short (*TbfT)[328] = (unsigned short(*)[328])(r2 + 13312);     // 2624 B
  __shared__ unsigned short bpb[4][264];
  __shared__ float Tbias[4];
  __shared__ float ps[64][3];
  __shared__ float cent[4][3];
  __shared__ float ctr[16], wid[16];
  __shared__ float w2l[64];

  int t = threadIdx.x, wg = blockIdx.x;
  long a0 = (long)wg * 64;
  int b0 = wg * 4;
  int lane = t & 63, w = t >> 6;
  int lrow = lane & 15, hi = lane >> 4, lk = hi * 8;
  floatx4 zero = {0.f, 0.f, 0.f, 0.f};

  // ---- load x -> xs (bf16), pos/centers/widths
  const float4* x4 = (const float4*)(x + a0 * 256);
  for (int m = 0; m < 16; ++m) {
    int f4 = t + 256 * m;
    int row = f4 >> 6, c4 = f4 & 63;
    float4 v = x4[f4];
    uint2 q;
    q.x = cvt2(v.x, v.y);
    q.y = cvt2(v.z, v.w);
    *(uint2*)&xs[row][c4 * 4] = q;
  }
  if (t < 192) ps[t / 3][t % 3] = pos[a0 * 3 + t];
  if (t >= 224 && t < 240) ctr[t - 224] = centers[t - 224];
  if (t >= 240) wid[t - 240] = widths[t - 240];
  float sblv = (lrow < 8) ? sb[lrow] : 0.f;
  __syncthreads();                                   // B1

  if (t < 12) {
    int b = t / 3, d = t % 3;
    float s = 0.f;
    for (int i = 0; i < 16; ++i) s += ps[b * 16 + i][d];
    cent[b][d] = s * 0.0625f;
  }
  __syncthreads();                                   // B2

  // ---- Phase S: PMA scores for atile w + per-block softmax -> wsm (xs pad)
  {
    floatx4 accs = zero;
#pragma unroll
    for (int k0 = 0; k0 < 8; ++k0) {
      short8 af = *(const short8*)&xs[16 * w + lrow][k0 * 32 + lk];
      short8 bf = *(const short8*)(A_bfT + lrow * 256 + k0 * 32 + lk);
      accs = __builtin_amdgcn_mfma_f32_16x16x32_bf16(af, bf, accs, 0, 0, 0);
    }
    float sv[4], e[4];
    float mx = -1e30f;
#pragma unroll
    for (int i = 0; i < 4; ++i) { sv[i] = accs[i] + sblv; mx = fmaxf(mx, sv[i]); }
    mx = fmaxf(mx, __shfl_xor(mx, 16));
    mx = fmaxf(mx, __shfl_xor(mx, 32));
    float se = 0.f;
#pragma unroll
    for (int i = 0; i < 4; ++i) { e[i] = __expf(sv[i] - mx); se += e[i]; }
    se += __shfl_xor(se, 16);
    se += __shfl_xor(se, 32);
    float inv = 1.f / fmaxf(se, 1e-20f);
    if (lrow < 8) {
#pragma unroll
      for (int i = 0; i < 4; ++i) xs[16 * w + hi * 4 + i][256 + lrow] = f2bfu(e[i] * inv);
    }
  }
  __syncthreads();                                   // B3

  // ---- Phase Y: pooled y via zero-masked K=32 MFMAs -> ysb (bf16)
  {
    int h = lrow & 7, bsel = lrow >> 3;
    short8 A1, A2;
#pragma unroll
    for (int j = 0; j < 8; ++j) {
      int atom = 8 * hi + j;
      unsigned short w1v = xs[atom][256 + h];
      unsigned short w2v = xs[32 + atom][256 + h];
      A1[j] = (bsel == (atom >> 4)) ? (short)w1v : (short)0;
      A2[j] = (bsel == (atom >> 4)) ? (short)w2v : (short)0;
    }
#pragma unroll
    for (int q = 0; q < 4; ++q) {
      int ct = 4 * w + q;
      int cb = ct * 16 + lrow;
      short8 B1, B2;
#pragma unroll
      for (int j = 0; j < 8; ++j) {
        B1[j] = (short)xs[8 * hi + j][cb];
        B2[j] = (short)xs[32 + 8 * hi + j][cb];
      }
      floatx4 d1 = __builtin_amdgcn_mfma_f32_16x16x32_bf16(A1, B1, zero, 0, 0, 0);
      floatx4 d2 = __builtin_amdgcn_mfma_f32_16x16x32_bf16(A2, B2, zero, 0, 0, 0);
#pragma unroll
      for (int i = 0; i < 4; ++i) {
        int r = hi * 4 + i;
        int hh = r & 7, bb = r >> 3;
        ysb[bb][hh][ct * 16 + lrow] = f2bfu(d1[i]);
        ysb[2 + bb][hh][ct * 16 + lrow] = f2bfu(d2[i]);
      }
    }
  }
  __syncthreads();                                   // B4

  // ---- BP via MFMA: D[block][j] = y[block][h][:] . WvT[j][:]. Wave w: heads 2w, 2w+1.
#pragma unroll
  for (int hh2 = 0; hh2 < 2; ++hh2) {
    int hd = 2 * w + hh2;
#pragma unroll
    for (int n = 0; n < 2; ++n) {
      floatx4 acc = zero;
#pragma unroll
      for (int ks = 0; ks < 8; ++ks) {
        short8 A = *(const short8*)&ysb[lrow & 3][hd][ks * 32 + lk];
        short8 B = *(const short8*)(WvTb + (hd * 32 + n * 16 + lrow) * 256 + ks * 32 + lk);
        acc = __builtin_amdgcn_mfma_f32_16x16x32_bf16(A, B, acc, 0, 0, 0);
      }
      if (hi == 0) {
        int col = hd * 32 + n * 16 + lrow;
        float bvc = bv[col];
#pragma unroll
        for (int i = 0; i < 4; ++i)
          bpb[i][col] = f2bfu(acc[i] + bvc);
      }
    }
  }
  __syncthreads();                                   // B5 (ysb dead)

  // ---- rbfl (bf16, k padded to 32) -> rbflb (in r2, after rbfpb region)
  if (t < 64) {
    int b = t >> 4;
    float dx = ps[t][0] - cent[b][0];
    float dy = ps[t][1] - cent[b][1];
    float dz = ps[t][2] - cent[b][2];
    float dist = sqrtf(dx * dx + dy * dy + dz * dz);
    for (int r = 0; r < 16; ++r) {
      float dd = dist - ctr[r];
      rbflb[t][r] = f2bfu(__expf(-dd * dd / (2.f * wid[r] * wid[r])));
      rbflb[t][16 + r] = 0;
    }
  }
  __syncthreads();                                   // B5a

  // ---- rbfp = rbfl @ geomT^T + geom_b via MFMA -> rbfpb
  {
    short8 A = *(const short8*)&rbflb[16 * w + lrow][lk];
#pragma unroll
    for (int qt = 0; qt < 4; ++qt) {
      short8 B = *(const short8*)(geomT + (qt * 16 + lrow) * 32 + lk);
      floatx4 d = __builtin_amdgcn_mfma_f32_16x16x32_bf16(A, B, zero, 0, 0, 0);
      float gb = geom_b[qt * 16 + lrow];
#pragma unroll
      for (int i = 0; i < 4; ++i)
        rbfpb[16 * w + hi * 4 + i][qt * 16 + lrow] = f2bfu(d[i] + gb);
    }
  }
  // ---- T via MFMA: T[block][c] = bp[block][:] . MMT[c][:] + vb2[c] -> TbfT (LDS)
  for (int ct = w; ct < 21; ct += 4) {
    floatx4 acc = zero;
#pragma unroll
    for (int ks = 0; ks < 8; ++ks) {
      short8 A = *(const short8*)&bpb[lrow & 3][ks * 32 + lk];
      short8 B = *(const short8*)(MMTb + (ct * 16 + lrow) * 256 + ks * 32 + lk);
      acc = __builtin_amdgcn_mfma_f32_16x16x32_bf16(A, B, acc, 0, 0, 0);
    }
    if (hi == 0) {
      int c = ct * 16 + lrow;
      if (c <= 320) {
        float vb = vb2[c];
        if (c < 320) {
#pragma unroll
          for (int i = 0; i < 4; ++i) TbfT[i][c] = f2bfu(acc[i] + vb);
        } else {
#pragma unroll
          for (int i = 0; i < 4; ++i) Tbias[i] = acc[i] + vb;
        }
      }
    }
  }
  __syncthreads();                                   // B6

  // ---- cross-attn scores: D[atom][j] = Xaug[atom,:] . T[j,:] (col j==w used)
  {
    floatx4 acc = zero;
#pragma unroll
    for (int k0 = 0; k0 < 8; ++k0) {
      short8 af = *(const short8*)&xs[16 * w + lrow][k0 * 32 + lk];
      short8 bf = *(const short8*)&TbfT[lrow & 3][k0 * 32 + lk];
      acc = __builtin_amdgcn_mfma_f32_16x16x32_bf16(af, bf, acc, 0, 0, 0);
    }
#pragma unroll
    for (int kq = 0; kq < 2; ++kq) {
      short8 af = *(const short8*)&rbfpb[16 * w + lrow][kq * 32 + lk];
      short8 bf = *(const short8*)&TbfT[lrow & 3][256 + kq * 32 + lk];
      acc = __builtin_amdgcn_mfma_f32_16x16x32_bf16(af, bf, acc, 0, 0, 0);
    }
    float tb = Tbias[w];
    float sv[4], e[4];
    float mx = -1e30f;
#pragma unroll
    for (int i = 0; i < 4; ++i) { sv[i] = (acc[i] + tb) * 0.0625f; mx = fmaxf(mx, sv[i]); }
    mx = fmaxf(mx, __shfl_xor(mx, 16));
    mx = fmaxf(mx, __shfl_xor(mx, 32));
    float se = 0.f;
#pragma unroll
    for (int i = 0; i < 4; ++i) { e[i] = __expf(sv[i] - mx); se += e[i]; }
    se += __shfl_xor(se, 16);
    se += __shfl_xor(se, 32);
    float inv = 1.f / fmaxf(se, 1e-20f);
    if (lrow == w) {
#pragma unroll
      for (int i = 0; i < 4; ++i) w2l[16 * w + hi * 4 + i] = e[i] * inv;
    }
  }
  __syncthreads();                                   // B7

  // ---- z: weighted pooling (f32 accum; rbfp part from bf16 rbfpb)
  for (int b = 0; b < 4; ++b) {
    float zv = 0.f;
    for (int i = 0; i < 16; ++i) zv += w2l[b * 16 + i] * bfu2f(xs[b * 16 + i][t]);
    z_f[(long)(b0 + b) * 320 + t] = zv;
  }
  {
    int q = t & 63, b = t >> 6;
    float zq = 0.f;
    for (int i = 0; i < 16; ++i) zq += w2l[b * 16 + i] * bfu2f(rbfpb[b * 16 + i][q]);
    z_f[(long)(b0 + b) * 320 + 256 + q] = zq;
  }
}

// ---------------- Gb2 v3 (MFMA): upd = relu(z@CV1+cb1)@cmlp_w2 + cmlp_b2
// 16 blocks / wg. M=16(blocks) x N=256 x K=320/256 via 16x16x32 bf16 MFMA.
__global__ __launch_bounds__(256, 4) void gb2(const float* __restrict__ z_f,
    const unsigned short* __restrict__ CV1Tb, const float* __restrict__ cb1,
    const unsigned short* __restrict__ W2mTb, const float* __restrict__ b2m,
    float* __restrict__ upd) {
  __shared__ unsigned short zb[16][328];   // 656B stride (164 dw = 4 mod 32)
  __shared__ unsigned short prb[16][264];  // 528B stride
  int t = threadIdx.x;
  int B0 = blockIdx.x * 16;
  int lane = t & 63, w = t >> 6;
  int lrow = lane & 15, hi = lane >> 4, lk = hi * 8;
  floatx4 zero = {0.f, 0.f, 0.f, 0.f};

  for (int idx = t; idx < 16 * 320; idx += 256) {
    int r = idx / 320, c = idx - r * 320;
    zb[r][c] = f2bfu(z_f[(long)(B0 + r) * 320 + c]);
  }
  __syncthreads();

  // GEMM1 + relu -> prb (bf16). Wave w owns out-col tiles w*4 .. w*4+3.
#pragma unroll
  for (int tt = 0; tt < 4; ++tt) {
    int colt = w * 4 + tt;
    floatx4 acc = zero;
    const unsigned short* ap = CV1Tb + (colt * 16 + lrow) * 320 + lk;
#pragma unroll
    for (int ks = 0; ks < 10; ++ks) {
      short8 A = *(const short8*)(ap + ks * 32);
      short8 B = *(const short8*)&zb[lrow][ks * 32 + lk];
      acc = __builtin_amdgcn_mfma_f32_16x16x32_bf16(A, B, acc, 0, 0, 0);
    }
    float4 cbv = ((const float4*)cb1)[colt * 4 + hi];
    float r0 = fmaxf(acc[0] + cbv.x, 0.f);
    float r1 = fmaxf(acc[1] + cbv.y, 0.f);
    float r2 = fmaxf(acc[2] + cbv.z, 0.f);
    float r3 = fmaxf(acc[3] + cbv.w, 0.f);
    uint2 q;
    q.x = cvt2(r0, r1);
    q.y = cvt2(r2, r3);
    *(uint2*)&prb[lrow][colt * 16 + hi * 4] = q;
  }
  __syncthreads();

  // GEMM2 -> upd (f32, float4 stores)
#pragma unroll
  for (int tt = 0; tt < 4; ++tt) {
    int colt = w * 4 + tt;
    floatx4 acc = zero;
    const unsigned short* ap = W2mTb + (colt * 16 + lrow) * 256 + lk;
#pragma unroll
    for (int ks = 0; ks < 8; ++ks) {
      short8 A = *(const short8*)(ap + ks * 32);
      short8 B = *(const short8*)&prb[lrow][ks * 32 + lk];
      acc = __builtin_amdgcn_mfma_f32_16x16x32_bf16(A, B, acc, 0, 0, 0);
    }
    float4 b2v = ((const float4*)b2m)[colt * 4 + hi];
    float4 st;
    st.x = acc[0] + b2v.x;
    st.y = acc[1] + b2v.y;
    st.z = acc[2] + b2v.z;
    st.w = acc[3] + b2v.w;
    *(float4*)&upd[(long)(B0 + lrow) * 256 + colt * 16 + hi * 4] = st;
  }
}

// ---------------- KF v4 (proven): LN1 + FFN (bf16 MFMA) + residual + LN2
__global__ __launch_bounds__(512, 4) void kf(const float* __restrict__ x,
    const float* __restrict__ upd, const unsigned short* __restrict__ W1t,
    const unsigned short* __restrict__ W2t, const float* __restrict__ b1,
    const float* __restrict__ b2, const float* __restrict__ g1,
    const float* __restrict__ be1, const float* __restrict__ g2,
    const float* __restrict__ be2, float* __restrict__ out) {
  __shared__ unsigned short x1s[64][264];  // post-LN1 (bf16), stride 528B (132 dw ≡ 4 mod 32)
  __shared__ unsigned short hs[64][136];   // 128-wide hidden slice, stride 272B (68 dw ≡ 4 mod 32)
  int t = threadIdx.x, wg = blockIdx.x;
  long a0 = (long)wg * 64;
  int b0 = wg * 4;
  int lane = t & 63, w = t >> 6;           // w in 0..7
  int lrow = lane & 15, hi = lane >> 4;    // hi in 0..3
  int lk = hi * 8;

  // ---- LN1: wave w handles rows w*8 .. w*8+7
  {
    float4 gv1 = ((const float4*)g1)[lane];
    float4 bv1 = ((const float4*)be1)[lane];
#pragma unroll
    for (int rr = 0; rr < 8; ++rr) {
      int row = w * 8 + rr;
      float4 xv = ((const float4*)(x + (a0 + row) * 256))[lane];
      float4 uv = ((const float4*)(upd + (long)(b0 + (row >> 4)) * 256))[lane];
      float4 v;
      v.x = xv.x + uv.x; v.y = xv.y + uv.y; v.z = xv.z + uv.z; v.w = xv.w + uv.w;
      float s = v.x + v.y + v.z + v.w;
      float sq = v.x * v.x + v.y * v.y + v.z * v.z + v.w * v.w;
#pragma unroll
      for (int d = 1; d < 64; d <<= 1) { s += __shfl_xor(s, d); sq += __shfl_xor(sq, d); }
      float mu = s * (1.f / 256.f);
      float var = sq * (1.f / 256.f) - mu * mu;
      float rstd = rsqrtf(fmaxf(var, 0.f) + 1e-5f);
      uint2 q;
      q.x = cvt2((v.x - mu) * rstd * gv1.x + bv1.x, (v.y - mu) * rstd * gv1.y + bv1.y);
      q.y = cvt2((v.z - mu) * rstd * gv1.z + bv1.z, (v.w - mu) * rstd * gv1.w + bv1.w);
      *(uint2*)&x1s[row][lane * 4] = q;
    }
  }
  __syncthreads();

  floatx4 zero = {0.f, 0.f, 0.f, 0.f};
  floatx4 acc2[2][4];  // [cb][rb]: D[outcol][atom]
#pragma unroll
  for (int cb = 0; cb < 2; ++cb)
    for (int rb = 0; rb < 4; ++rb) acc2[cb][rb] = zero;

  for (int s = 0; s < 4; ++s) {
    // --- hoist GEMM1 weight frags: wave's 16 hidden cols, full K=256
    int hc = s * 128 + w * 16 + lrow;
    short8 wf[8];
#pragma unroll
    for (int k0 = 0; k0 < 8; ++k0)
      wf[k0] = *(const short8*)(W1t + hc * 256 + k0 * 32 + lk);
    // --- GEMM1: A=W1 (m=hid), B=x (n=atom) -> D[hid][atom]
    floatx4 acc1[4] = {zero, zero, zero, zero};
#pragma unroll
    for (int k0 = 0; k0 < 8; ++k0) {
      short8 af0 = *(const short8*)&x1s[0 + lrow][k0 * 32 + lk];
      short8 af1 = *(const short8*)&x1s[16 + lrow][k0 * 32 + lk];
      short8 af2 = *(const short8*)&x1s[32 + lrow][k0 * 32 + lk];
      short8 af3 = *(const short8*)&x1s[48 + lrow][k0 * 32 + lk];
      acc1[0] = __builtin_amdgcn_mfma_f32_16x16x32_bf16(wf[k0], af0, acc1[0], 0, 0, 0);
      acc1[1] = __builtin_amdgcn_mfma_f32_16x16x32_bf16(wf[k0], af1, acc1[1], 0, 0, 0);
      acc1[2] = __builtin_amdgcn_mfma_f32_16x16x32_bf16(wf[k0], af2, acc1[2], 0, 0, 0);
      acc1[3] = __builtin_amdgcn_mfma_f32_16x16x32_bf16(wf[k0], af3, acc1[3], 0, 0, 0);
    }
    // --- hoist GEMM2 weight frags (latency hides under barriers + hs writes)
    short8 wf2[8];
#pragma unroll
    for (int cb = 0; cb < 2; ++cb)
      for (int ks = 0; ks < 4; ++ks)
        wf2[cb * 4 + ks] = *(const short8*)(W2t + (w * 32 + cb * 16 + lrow) * 512 + s * 128 + ks * 32 + lk);
    // bias1 for hid = s*128 + w*16 + hi*4 + i
    float4 b4 = ((const float4*)b1)[s * 32 + w * 4 + hi];
    __syncthreads();  // previous GEMM2 finished reading hs
    // lane holds D[hid = w*16+hi*4+i][atom = rb*16+lrow] -> packed b64 store
#pragma unroll
    for (int rb = 0; rb < 4; ++rb) {
      float r0 = fmaxf(acc1[rb][0] + b4.x, 0.f);
      float r1 = fmaxf(acc1[rb][1] + b4.y, 0.f);
      float r2 = fmaxf(acc1[rb][2] + b4.z, 0.f);
      float r3 = fmaxf(acc1[rb][3] + b4.w, 0.f);
      uint2 q;
      q.x = cvt2(r0, r1);
      q.y = cvt2(r2, r3);
      *(uint2*)&hs[rb * 16 + lrow][w * 16 + hi * 4] = q;
    }
    __syncthreads();
    // --- GEMM2 partial: A=W2 (m=outcol), B=hs (n=atom), K-slice = this phase's 128
#pragma unroll
    for (int ks = 0; ks < 4; ++ks) {
      short8 a20 = *(const short8*)&hs[0 + lrow][ks * 32 + lk];
      short8 a21 = *(const short8*)&hs[16 + lrow][ks * 32 + lk];
      short8 a22 = *(const short8*)&hs[32 + lrow][ks * 32 + lk];
      short8 a23 = *(const short8*)&hs[48 + lrow][ks * 32 + lk];
#pragma unroll
      for (int cb = 0; cb < 2; ++cb) {
        acc2[cb][0] = __builtin_amdgcn_mfma_f32_16x16x32_bf16(wf2[cb * 4 + ks], a20, acc2[cb][0], 0, 0, 0);
        acc2[cb][1] = __builtin_amdgcn_mfma_f32_16x16x32_bf16(wf2[cb * 4 + ks], a21, acc2[cb][1], 0, 0, 0);
        acc2[cb][2] = __builtin_amdgcn_mfma_f32_16x16x32_bf16(wf2[cb * 4 + ks], a22, acc2[cb][2], 0, 0, 0);
        acc2[cb][3] = __builtin_amdgcn_mfma_f32_16x16x32_bf16(wf2[cb * 4 + ks], a23, acc2[cb][3], 0, 0, 0);
      }
    }
  }

  // epilogue: lane holds D[outcol = w*32+cb*16+hi*4+i][atom = rb*16+lrow]
  // residual (bf16 x1) + bias2, packed b64 RMW into x1s
#pragma unroll
  for (int cb = 0; cb < 2; ++cb) {
    float4 b4 = ((const float4*)b2)[w * 8 + cb * 4 + hi];
    int colb = w * 32 + cb * 16 + hi * 4;
#pragma unroll
    for (int rb = 0; rb < 4; ++rb) {
      int atom = rb * 16 + lrow;
      ushort4 old = *(const ushort4*)&x1s[atom][colb];
      float r0 = acc2[cb][rb][0] + b4.x + bfu2f(old.x);
      float r1 = acc2[cb][rb][1] + b4.y + bfu2f(old.y);
      float r2 = acc2[cb][rb][2] + b4.z + bfu2f(old.z);
      float r3 = acc2[cb][rb][3] + b4.w + bfu2f(old.w);
      uint2 q;
      q.x = cvt2(r0, r1);
      q.y = cvt2(r2, r3);
      *(uint2*)&x1s[atom][colb] = q;
    }
  }
  __syncthreads();

  // ---- LN2 + coalesced store: wave w handles rows w*8 .. w*8+7
  {
    float4 gv2 = ((const float4*)g2)[lane];
    float4 bv2 = ((const float4*)be2)[lane];
#pragma unroll
    for (int rr = 0; rr < 8; ++rr) {
      int row = w * 8 + rr;
      ushort4 u = *(const ushort4*)&x1s[row][lane * 4];
      float v0 = bfu2f(u.x), v1 = bfu2f(u.y), v2 = bfu2f(u.z), v3 = bfu2f(u.w);
      float s = v0 + v1 + v2 + v3;
      float sq = v0 * v0 + v1 * v1 + v2 * v2 + v3 * v3;
#pragma unroll
      for (int d = 1; d < 64; d <<= 1) { s += __shfl_xor(s, d); sq += __shfl_xor(sq, d); }
      float mu = s * (1.f / 256.f);
      float var = sq * (1.f / 256.f) - mu * mu;
      float rstd = rsqrtf(fmaxf(var, 0.f) + 1e-5f);
      float4 o;
      o.x = (v0 - mu) * rstd * gv2.x + bv2.x;
      o.y = (v1 - mu) * rstd * gv2.y + bv2.y;
      o.z = (v2 - mu) * rstd * gv2.z + bv2.z;
      o.w = (v3 - mu) * rstd * gv2.w + bv2.w;
      ((float4*)(out + (a0 + row) * 256))[lane] = o;
    }
  }
}

extern "C" void kernel_launch(void* const* d_in, const int* in_sizes, int n_in,
                              void* d_out, int out_size, void* d_ws, size_t ws_size,
                              hipStream_t stream) {
  (void)in_sizes; (void)n_in; (void)out_size; (void)ws_size;
  const float* x    = (const float*)d_in[0];
  const float* pos  = (const float*)d_in[1];
  const float* seed = (const float*)d_in[4];
  const float* Wq   = (const float*)d_in[5];
  const float* bq   = (const float*)d_in[6];
  const float* Wk   = (const float*)d_in[7];
  const float* bk   = (const float*)d_in[8];
  const float* Wv   = (const float*)d_in[9];
  const float* bv   = (const float*)d_in[10];
  const float* Wo   = (const float*)d_in[11];
  const float* bo   = (const float*)d_in[12];
  const float* centers = (const float*)d_in[13];
  const float* widths  = (const float*)d_in[14];
  const float* geom_w  = (const float*)d_in[15];
  const float* geom_b  = (const float*)d_in[16];
  const float* cq_w = (const float*)d_in[17];
  const float* cq_b = (const float*)d_in[18];
  const float* ck_w = (const float*)d_in[19];
  const float* ck_b = (const float*)d_in[20];
  const float* cv_w = (const float*)d_in[21];
  const float* cv_b = (const float*)d_in[22];
  const float* w1m  = (const float*)d_in[23];
  const float* b1m  = (const float*)d_in[24];
  const float* w2m  = (const float*)d_in[25];
  const float* b2m  = (const float*)d_in[26];
  const float* fw1  = (const float*)d_in[27];
  const float* fb1  = (const float*)d_in[28];
  const float* fw2  = (const float*)d_in[29];
  const float* fb2  = (const float*)d_in[30];
  const float* g1   = (const float*)d_in[31];
  const float* be1  = (const float*)d_in[32];
  const float* g2   = (const float*)d_in[33];
  const float* be2  = (const float*)d_in[34];

  float* ws = (float*)d_ws;
  float* sb = ws + 0;                                       // 64
  unsigned short* A_bfT = (unsigned short*)(ws + 64);       // 16*256 bf16 -> ends 2112
  float* M     = ws + 2112;     // 256*336 = 86016 -> ends 88128
  float* vbias = ws + 88128;    // 352 -> ends 88480
  unsigned short* MMTb = (unsigned short*)(ws + 88480);     // 336*256 bf16 = 43008 floats -> ends 131488
  float* vb2   = ws + 131488;   // 352 -> ends 131840
  unsigned short* CV1Tb = (unsigned short*)(ws + 131840);   // 256*320 bf16 = 40960 floats -> ends 172800
  float* cb1   = ws + 172800;   // 256 -> ends 173056
  unsigned short* W1t = (unsigned short*)(ws + 173056);     // 512*256 bf16 = 65536 floats -> ends 238592
  unsigned short* W2t = (unsigned short*)(ws + 238592);     // 256*512 bf16 = 65536 floats -> ends 304128
  unsigned short* W2mTb = (unsigned short*)(ws + 304128);   // 256*256 bf16 = 32768 floats -> ends 336896
  unsigned short* WvTb = (unsigned short*)(ws + 336896);    // 256*256 bf16 = 32768 floats -> ends 369664
  float* updw = ws + 369664;                                // 8192*256 f32 -> ends 2466816
  unsigned short* geomT = (unsigned short*)(ws + 2466816);  // 64*32 bf16
  // total ws use: ~10 MB

  // scratch inside d_out (134 MB, fully overwritten by kf at the end):
  float* outp = (float*)d_out;
  float* zf  = outp + 21626880;    // 8192*320 f32 = 2,621,440 (ends 24,248,320 < 33,554,432)

  prepA<<<dim3(1867), dim3(352), 0, stream>>>(seed, Wq, bq, Wk, bk, A_bfT, sb,
      cq_w, cq_b, ck_w, ck_b, M, vbias,
      cv_w, cv_b, w1m, b1m, CV1Tb, cb1,
      fw1, fw2, w2m, geom_w, W1t, W2t, W2mTb, geomT, Wv, WvTb);
  kp2<<<dim3(257), dim3(352), 0, stream>>>(Wo, bo, M, vbias, MMTb, vb2);
  kgm3<<<dim3(2048), dim3(256), 0, stream>>>(x, pos, A_bfT, sb, WvTb, bv, MMTb, vb2,
      centers, widths, geomT, geom_b, zf);
  gb2<<<dim3(512), dim3(256), 0, stream>>>(zf, CV1Tb, cb1, W2mTb, b2m, updw);
  kf<<<dim3(2048), dim3(512), 0, stream>>>(x, updw, W1t, W2t, fb1, fb2, g1, be1, g2, be2, outp);
}

// Round 17
// 323.829 us; speedup vs baseline: 1.0030x; 1.0030x over previous
//
#include <hip/hip_runtime.h>
#include <hip/hip_bf16.h>

// Sizes (fixed by the problem)
#define NATOMS 131072
#define NBLK   8192
#define HDIM   256
#define NHEAD  8
#define TDIM   336   // 320 aug dims + 1 (ck_b . Q) + pad

typedef __attribute__((ext_vector_type(8))) short short8;
typedef __attribute__((ext_vector_type(4))) float floatx4;

__device__ __forceinline__ float bfu2f(unsigned short u) {
  unsigned int v = ((unsigned int)u) << 16;
  return __builtin_bit_cast(float, v);
}
__device__ __forceinline__ unsigned short f2bfu(float f) {
  unsigned int u = __builtin_bit_cast(unsigned int, f);
  u += 0x7fffu + ((u >> 16) & 1u);
  return (unsigned short)(u >> 16);
}
// packs bf16(a) into low 16, bf16(b) into high 16 (RNE)
__device__ __forceinline__ unsigned int cvt2(float a, float b) {
  unsigned int r;
  asm("v_cvt_pk_bf16_f32 %0, %1, %2" : "=v"(r) : "v"(a), "v"(b));
  return r;
}

// ---------------- prepA: fused independent preps.
// b in [0,9): k0_prep ; [9,265): kp1 ; [265,586): kp3 (-> CV1Tb bf16 transposed) ;
// [586,1611): kcast {W1t, W2t, geomT, W2mTb} ; [1611,1867): WvTb.
__global__ __launch_bounds__(352) void prepA(
    const float* __restrict__ seed, const float* __restrict__ Wq,
    const float* __restrict__ bq, const float* __restrict__ Wk,
    const float* __restrict__ bk, unsigned short* __restrict__ A_bfT,
    float* __restrict__ sb,
    const float* __restrict__ cq_w, const float* __restrict__ cq_b,
    const float* __restrict__ ck_w, const float* __restrict__ ck_b,
    float* __restrict__ M, float* __restrict__ vbias,
    const float* __restrict__ cv_w, const float* __restrict__ cv_b,
    const float* __restrict__ w1m, const float* __restrict__ b1m,
    unsigned short* __restrict__ CV1Tb, float* __restrict__ cb1,
    const float* __restrict__ fw1, const float* __restrict__ fw2,
    const float* __restrict__ w2m, const float* __restrict__ geom_w,
    unsigned short* __restrict__ W1t, unsigned short* __restrict__ W2t,
    unsigned short* __restrict__ W2mTb, unsigned short* __restrict__ geomT,
    const float* __restrict__ Wv, unsigned short* __restrict__ WvTb) {
  __shared__ float row[256];
  int t = threadIdx.x, b = blockIdx.x;
  if (b < 9) {
    // ---- k0: q = seed@Wq+bq ; A_bfT ; sb
    if (t < 256) {
      float acc = bq[t];
      for (int c = 0; c < 256; ++c) acc += seed[c] * Wq[c * 256 + t];
      row[t] = acc;
    }
    __syncthreads();
    const float scale = 0.17677669529663687f;  // 1/sqrt(32)
    if (b < 8) {
      if (t < 256) {
        int o = b * 256 + t;
        int c = o >> 3, h = o & 7;
        float a = 0.f;
        for (int d = 0; d < 32; ++d) a += Wk[c * 256 + h * 32 + d] * row[h * 32 + d];
        A_bfT[h * 256 + c] = f2bfu(a * scale);
      }
    } else {
      if (t < 8) {
        float a = 0.f;
        for (int d = 0; d < 32; ++d) a += bk[t * 32 + d] * row[t * 32 + d];
        sb[t] = a * scale;
      }
      if (t < 256)
        for (int idx = t; idx < 2048; idx += 256) A_bfT[2048 + idx] = 0;
    }
  } else if (b < 265) {
    // ---- kp1: M[i][c] = cq_w[i,:] . ckT[:,c]
    int i = b - 9;
    if (t < 256) row[t] = cq_w[i * 256 + t];
    __syncthreads();
    if (t < TDIM) {
      float a = 0.f;
      if (t < 320) { const float* w = ck_w + t * 256; for (int j = 0; j < 256; ++j) a += row[j] * w[j]; }
      else if (t == 320) { for (int j = 0; j < 256; ++j) a += row[j] * ck_b[j]; }
      M[i * TDIM + t] = a;
    }
    if (i == 0) {
      __syncthreads();
      if (t < 256) row[t] = cq_b[t];
      __syncthreads();
      if (t < TDIM) {
        float a = 0.f;
        if (t < 320) { const float* w = ck_w + t * 256; for (int j = 0; j < 256; ++j) a += row[j] * w[j]; }
        else if (t == 320) { for (int j = 0; j < 256; ++j) a += row[j] * ck_b[j]; }
        vbias[t] = a;
      }
    }
  } else if (b < 586) {
    // ---- kp3: CV1Tb[j][k] = bf16(cv_w[k,:] . w1m[:,j]) ; block 320: cb1 f32
    int k = b - 265;
    if (t < 256) row[t] = (k < 320) ? cv_w[k * 256 + t] : cv_b[t];
    __syncthreads();
    if (t < 256) {
      float a = 0.f;
      for (int i = 0; i < 256; ++i) a += row[i] * w1m[i * 256 + t];
      if (k < 320) CV1Tb[t * 320 + k] = f2bfu(a);
      else cb1[t] = a + b1m[t];
    }
  } else if (b < 1611) {
    // ---- kcast
    int bb = b - 586;
    if (bb < 512) {
      if (t < 256) W1t[bb * 256 + t] = f2bfu(fw1[t * 512 + bb]);
    } else if (bb < 768) {
      int n = bb - 512;
      if (t < 256)
        for (int m = 0; m < 2; ++m) {
          int k = t + 256 * m;
          W2t[n * 512 + k] = f2bfu(fw2[k * 256 + n]);
        }
    } else if (bb == 768) {
      if (t < 256)
        for (int idx = t; idx < 2048; idx += 256) {
          int q = idx >> 5, r = idx & 31;
          geomT[idx] = (r < 16) ? f2bfu(geom_w[r * 64 + q]) : (unsigned short)0;
        }
    } else {
      int n = bb - 769;
      if (t < 256) W2mTb[n * 256 + t] = f2bfu(w2m[t * 256 + n]);
    }
  } else {
    // ---- WvTb[j][c] = bf16(Wv[c][j])
    int j = b - 1611;
    if (t < 256) WvTb[j * 256 + t] = f2bfu(Wv[t * 256 + j]);
  }
}

// ---------------- Kp2: MMTb[c][p] = bf16(Wo[p,:] . M[:,c]) ; block 256: vb2[c] = bo.M[:,c] + vbias[c]
__global__ __launch_bounds__(352) void kp2(const float* __restrict__ Wo,
    const float* __restrict__ bo, const float* __restrict__ M,
    const float* __restrict__ vbias, unsigned short* __restrict__ MMTb,
    float* __restrict__ vb2) {
  __shared__ float row[256];
  int p = blockIdx.x, t = threadIdx.x;
  const float* src = (p < 256) ? (Wo + p * 256) : bo;
  if (t < 256) row[t] = src[t];
  __syncthreads();
  if (t < TDIM) {
    float a = 0.f;
    for (int i = 0; i < 256; ++i) a += row[i] * M[i * TDIM + t];
    if (p < 256) MMTb[t * 256 + p] = f2bfu(a);
    else vb2[t] = a + vbias[t];
  }
}

// ---------------- KGM3 (round-15 layout): fused kgm + kg3, all heavy phases MFMA.
// Per wg: 64 atoms = 4 blocks. x read ONCE; T lives only in LDS; z written bf16.
// Phases: load -> cent -> {rbfl, S} -> Y -> BP -> {rbfp, T} -> scores -> z.
__global__ __launch_bounds__(256) void kgm3(const float* __restrict__ x,
    const float* __restrict__ pos,
    const unsigned short* __restrict__ A_bfT, const float* __restrict__ sb,
    const unsigned short* __restrict__ WvTb, const float* __restrict__ bv,
    const unsigned short* __restrict__ MMTb, const float* __restrict__ vb2,
    const float* __restrict__ centers, const float* __restrict__ widths,
    const unsigned short* __restrict__ geomT, const float* __restrict__ geom_b,
    unsigned short* __restrict__ zbf) {
  __shared__ unsigned short xs[64][264];            // persists through z phase
  __shared__ __align__(16) char r2[16896];          // ysb -> rbfpb
  unsigned short (*ysb)[8][264] = (unsigned short(*)[8][264])r2;   // 16896 B
  unsigned short (*rbfpb)[72] = (unsigned short(*)[72])r2;         // 9216 B
  __shared__ unsigned short rbflb[64][32];
  __shared__ unsigned short bpb[4][264];
  __shared__ unsigned short TbfT[4][328];
  __shared__ float Tbias[4];
  __shared__ unsigned short wsm[64][8];
  __shared__ float ps[64][3];
  __shared__ float cent[4][3];
  __shared__ float ctr[16], wid[16];
  __shared__ float w2l[64];

  int t = threadIdx.x, wg = blockIdx.x;
  long a0 = (long)wg * 64;
  int b0 = wg * 4;
  int lane = t & 63, w = t >> 6;
  int lrow = lane & 15, hi = lane >> 4, lk = hi * 8;
  floatx4 zero = {0.f, 0.f, 0.f, 0.f};

  // ---- load x -> xs (bf16), pos/centers/widths
  const float4* x4 = (const float4*)(x + a0 * 256);
  for (int m = 0; m < 16; ++m) {
    int f4 = t + 256 * m;
    int row = f4 >> 6, c4 = f4 & 63;
    float4 v = x4[f4];
    uint2 q;
    q.x = cvt2(v.x, v.y);
    q.y = cvt2(v.z, v.w);
    *(uint2*)&xs[row][c4 * 4] = q;
  }
  if (t < 192) ps[t / 3][t % 3] = pos[a0 * 3 + t];
  if (t >= 224 && t < 240) ctr[t - 224] = centers[t - 224];
  if (t >= 240) wid[t - 240] = widths[t - 240];
  float sblv = (lrow < 8) ? sb[lrow] : 0.f;
  __syncthreads();                                   // B1

  if (t < 12) {
    int b = t / 3, d = t % 3;
    float s = 0.f;
    for (int i = 0; i < 16; ++i) s += ps[b * 16 + i][d];
    cent[b][d] = s * 0.0625f;
  }
  __syncthreads();                                   // B2

  // ---- rbfl (bf16, k padded to 32)
  if (t < 64) {
    int b = t >> 4;
    float dx = ps[t][0] - cent[b][0];
    float dy = ps[t][1] - cent[b][1];
    float dz = ps[t][2] - cent[b][2];
    float dist = sqrtf(dx * dx + dy * dy + dz * dz);
    for (int r = 0; r < 16; ++r) {
      float dd = dist - ctr[r];
      rbflb[t][r] = f2bfu(__expf(-dd * dd / (2.f * wid[r] * wid[r])));
      rbflb[t][16 + r] = 0;
    }
  }

  // ---- Phase S: PMA scores for atile w + per-block softmax -> wsm
  {
    floatx4 accs = zero;
#pragma unroll
    for (int k0 = 0; k0 < 8; ++k0) {
      short8 af = *(const short8*)&xs[16 * w + lrow][k0 * 32 + lk];
      short8 bf = *(const short8*)(A_bfT + lrow * 256 + k0 * 32 + lk);
      accs = __builtin_amdgcn_mfma_f32_16x16x32_bf16(af, bf, accs, 0, 0, 0);
    }
    float sv[4], e[4];
    float mx = -1e30f;
#pragma unroll
    for (int i = 0; i < 4; ++i) { sv[i] = accs[i] + sblv; mx = fmaxf(mx, sv[i]); }
    mx = fmaxf(mx, __shfl_xor(mx, 16));
    mx = fmaxf(mx, __shfl_xor(mx, 32));
    float se = 0.f;
#pragma unroll
    for (int i = 0; i < 4; ++i) { e[i] = __expf(sv[i] - mx); se += e[i]; }
    se += __shfl_xor(se, 16);
    se += __shfl_xor(se, 32);
    float inv = 1.f / fmaxf(se, 1e-20f);
    if (lrow < 8) {
#pragma unroll
      for (int i = 0; i < 4; ++i) wsm[16 * w + hi * 4 + i][lrow] = f2bfu(e[i] * inv);
    }
  }
  __syncthreads();                                   // B3

  // ---- Phase Y: pooled y via zero-masked K=32 MFMAs -> ysb (bf16)
  {
    int h = lrow & 7, bsel = lrow >> 3;
    short8 A1, A2;
#pragma unroll
    for (int j = 0; j < 8; ++j) {
      int atom = 8 * hi + j;
      unsigned short w1v = wsm[atom][h];
      unsigned short w2v = wsm[32 + atom][h];
      A1[j] = (bsel == (atom >> 4)) ? (short)w1v : (short)0;
      A2[j] = (bsel == (atom >> 4)) ? (short)w2v : (short)0;
    }
#pragma unroll
    for (int q = 0; q < 4; ++q) {
      int ct = 4 * w + q;
      int cb = ct * 16 + lrow;
      short8 B1, B2;
#pragma unroll
      for (int j = 0; j < 8; ++j) {
        B1[j] = (short)xs[8 * hi + j][cb];
        B2[j] = (short)xs[32 + 8 * hi + j][cb];
      }
      floatx4 d1 = __builtin_amdgcn_mfma_f32_16x16x32_bf16(A1, B1, zero, 0, 0, 0);
      floatx4 d2 = __builtin_amdgcn_mfma_f32_16x16x32_bf16(A2, B2, zero, 0, 0, 0);
#pragma unroll
      for (int i = 0; i < 4; ++i) {
        int r = hi * 4 + i;
        int hh = r & 7, bb = r >> 3;
        ysb[bb][hh][ct * 16 + lrow] = f2bfu(d1[i]);
        ysb[2 + bb][hh][ct * 16 + lrow] = f2bfu(d2[i]);
      }
    }
  }
  __syncthreads();                                   // B4

  // ---- BP via MFMA: D[block][j] = y[block][h][:] . WvT[j][:]. Wave w: heads 2w, 2w+1.
#pragma unroll
  for (int hh2 = 0; hh2 < 2; ++hh2) {
    int hd = 2 * w + hh2;
#pragma unroll
    for (int n = 0; n < 2; ++n) {
      floatx4 acc = zero;
#pragma unroll
      for (int ks = 0; ks < 8; ++ks) {
        short8 A = *(const short8*)&ysb[lrow & 3][hd][ks * 32 + lk];
        short8 B = *(const short8*)(WvTb + (hd * 32 + n * 16 + lrow) * 256 + ks * 32 + lk);
        acc = __builtin_amdgcn_mfma_f32_16x16x32_bf16(A, B, acc, 0, 0, 0);
      }
      if (hi == 0) {
        int col = hd * 32 + n * 16 + lrow;
        float bvc = bv[col];
#pragma unroll
        for (int i = 0; i < 4; ++i)
          bpb[i][col] = f2bfu(acc[i] + bvc);
      }
    }
  }
  __syncthreads();                                   // B5 (ysb dead)

  // ---- rbfp = rbfl @ geomT^T + geom_b via MFMA -> rbfpb (aliases ysb region)
  {
    short8 A = *(const short8*)&rbflb[16 * w + lrow][lk];
#pragma unroll
    for (int qt = 0; qt < 4; ++qt) {
      short8 B = *(const short8*)(geomT + (qt * 16 + lrow) * 32 + lk);
      floatx4 d = __builtin_amdgcn_mfma_f32_16x16x32_bf16(A, B, zero, 0, 0, 0);
      float gb = geom_b[qt * 16 + lrow];
#pragma unroll
      for (int i = 0; i < 4; ++i)
        rbfpb[16 * w + hi * 4 + i][qt * 16 + lrow] = f2bfu(d[i] + gb);
    }
  }
  // ---- T via MFMA: T[block][c] = bp[block][:] . MMT[c][:] + vb2[c] -> TbfT (LDS)
  for (int ct = w; ct < 21; ct += 4) {
    floatx4 acc = zero;
#pragma unroll
    for (int ks = 0; ks < 8; ++ks) {
      short8 A = *(const short8*)&bpb[lrow & 3][ks * 32 + lk];
      short8 B = *(const short8*)(MMTb + (ct * 16 + lrow) * 256 + ks * 32 + lk);
      acc = __builtin_amdgcn_mfma_f32_16x16x32_bf16(A, B, acc, 0, 0, 0);
    }
    if (hi == 0) {
      int c = ct * 16 + lrow;
      if (c <= 320) {
        float vb = vb2[c];
        if (c < 320) {
#pragma unroll
          for (int i = 0; i < 4; ++i) TbfT[i][c] = f2bfu(acc[i] + vb);
        } else {
#pragma unroll
          for (int i = 0; i < 4; ++i) Tbias[i] = acc[i] + vb;
        }
      }
    }
  }
  __syncthreads();                                   // B6

  // ---- cross-attn scores: D[atom][j] = Xaug[atom,:] . T[j,:] (col j==w used)
  {
    floatx4 acc = zero;
#pragma unroll
    for (int k0 = 0; k0 < 8; ++k0) {
      short8 af = *(const short8*)&xs[16 * w + lrow][k0 * 32 + lk];
      short8 bf = *(const short8*)&TbfT[lrow & 3][k0 * 32 + lk];
      acc = __builtin_amdgcn_mfma_f32_16x16x32_bf16(af, bf, acc, 0, 0, 0);
    }
#pragma unroll
    for (int kq = 0; kq < 2; ++kq) {
      short8 af = *(const short8*)&rbfpb[16 * w + lrow][kq * 32 + lk];
      short8 bf = *(const short8*)&TbfT[lrow & 3][256 + kq * 32 + lk];
      acc = __builtin_amdgcn_mfma_f32_16x16x32_bf16(af, bf, acc, 0, 0, 0);
    }
    float tb = Tbias[w];
    float sv[4], e[4];
    float mx = -1e30f;
#pragma unroll
    for (int i = 0; i < 4; ++i) { sv[i] = (acc[i] + tb) * 0.0625f; mx = fmaxf(mx, sv[i]); }
    mx = fmaxf(mx, __shfl_xor(mx, 16));
    mx = fmaxf(mx, __shfl_xor(mx, 32));
    float se = 0.f;
#pragma unroll
    for (int i = 0; i < 4; ++i) { e[i] = __expf(sv[i] - mx); se += e[i]; }
    se += __shfl_xor(se, 16);
    se += __shfl_xor(se, 32);
    float inv = 1.f / fmaxf(se, 1e-20f);
    if (lrow == w) {
#pragma unroll
      for (int i = 0; i < 4; ++i) w2l[16 * w + hi * 4 + i] = e[i] * inv;
    }
  }
  __syncthreads();                                   // B7

  // ---- z: weighted pooling (f32 accum) -> zbf (bf16; gb2 rounded to bf16 anyway)
  for (int b = 0; b < 4; ++b) {
    float zv = 0.f;
    for (int i = 0; i < 16; ++i) zv += w2l[b * 16 + i] * bfu2f(xs[b * 16 + i][t]);
    zbf[(long)(b0 + b) * 320 + t] = f2bfu(zv);
  }
  {
    int q = t & 63, b = t >> 6;
    float zq = 0.f;
    for (int i = 0; i < 16; ++i) zq += w2l[b * 16 + i] * bfu2f(rbfpb[b * 16 + i][q]);
    zbf[(long)(b0 + b) * 320 + 256 + q] = f2bfu(zq);
  }
}

// ---------------- Gb2 v4 (MFMA, bf16 z input): upd = relu(z@CV1+cb1)@cmlp_w2 + cmlp_b2
// 16 blocks / wg. M=16(blocks) x N=256 x K=320/256 via 16x16x32 bf16 MFMA.
__global__ __launch_bounds__(256, 4) void gb2(const unsigned short* __restrict__ zbf,
    const unsigned short* __restrict__ CV1Tb, const float* __restrict__ cb1,
    const unsigned short* __restrict__ W2mTb, const float* __restrict__ b2m,
    float* __restrict__ upd) {
  __shared__ unsigned short zb[16][328];   // 656B stride (164 dw = 4 mod 32)
  __shared__ unsigned short prb[16][264];  // 528B stride
  int t = threadIdx.x;
  int B0 = blockIdx.x * 16;
  int lane = t & 63, w = t >> 6;
  int lrow = lane & 15, hi = lane >> 4, lk = hi * 8;
  floatx4 zero = {0.f, 0.f, 0.f, 0.f};

  for (int idx = t; idx < 16 * 160; idx += 256) {
    int e = idx * 2;
    int r = e / 320, c = e - r * 320;
    *(ushort2*)&zb[r][c] = *(const ushort2*)(zbf + (long)(B0 + r) * 320 + c);
  }
  __syncthreads();

  // GEMM1 + relu -> prb (bf16). Wave w owns out-col tiles w*4 .. w*4+3.
#pragma unroll
  for (int tt = 0; tt < 4; ++tt) {
    int colt = w * 4 + tt;
    floatx4 acc = zero;
    const unsigned short* ap = CV1Tb + (colt * 16 + lrow) * 320 + lk;
#pragma unroll
    for (int ks = 0; ks < 10; ++ks) {
      short8 A = *(const short8*)(ap + ks * 32);
      short8 B = *(const short8*)&zb[lrow][ks * 32 + lk];
      acc = __builtin_amdgcn_mfma_f32_16x16x32_bf16(A, B, acc, 0, 0, 0);
    }
    float4 cbv = ((const float4*)cb1)[colt * 4 + hi];
    float r0 = fmaxf(acc[0] + cbv.x, 0.f);
    float r1 = fmaxf(acc[1] + cbv.y, 0.f);
    float r2 = fmaxf(acc[2] + cbv.z, 0.f);
    float r3 = fmaxf(acc[3] + cbv.w, 0.f);
    uint2 q;
    q.x = cvt2(r0, r1);
    q.y = cvt2(r2, r3);
    *(uint2*)&prb[lrow][colt * 16 + hi * 4] = q;
  }
  __syncthreads();

  // GEMM2 -> upd (f32, float4 stores)
#pragma unroll
  for (int tt = 0; tt < 4; ++tt) {
    int colt = w * 4 + tt;
    floatx4 acc = zero;
    const unsigned short* ap = W2mTb + (colt * 16 + lrow) * 256 + lk;
#pragma unroll
    for (int ks = 0; ks < 8; ++ks) {
      short8 A = *(const short8*)(ap + ks * 32);
      short8 B = *(const short8*)&prb[lrow][ks * 32 + lk];
      acc = __builtin_amdgcn_mfma_f32_16x16x32_bf16(A, B, acc, 0, 0, 0);
    }
    float4 b2v = ((const float4*)b2m)[colt * 4 + hi];
    float4 st;
    st.x = acc[0] + b2v.x;
    st.y = acc[1] + b2v.y;
    st.z = acc[2] + b2v.z;
    st.w = acc[3] + b2v.w;
    *(float4*)&upd[(long)(B0 + lrow) * 256 + colt * 16 + hi * 4] = st;
  }
}

// ---------------- KF v4 (proven): LN1 + FFN (bf16 MFMA) + residual + LN2
__global__ __launch_bounds__(512, 4) void kf(const float* __restrict__ x,
    const float* __restrict__ upd, const unsigned short* __restrict__ W1t,
    const unsigned short* __restrict__ W2t, const float* __restrict__ b1,
    const float* __restrict__ b2, const float* __restrict__ g1,
    const float* __restrict__ be1, const float* __restrict__ g2,
    const float* __restrict__ be2, float* __restrict__ out) {
  __shared__ unsigned short x1s[64][264];  // post-LN1 (bf16), stride 528B (132 dw ≡ 4 mod 32)
  __shared__ unsigned short hs[64][136];   // 128-wide hidden slice, stride 272B (68 dw ≡ 4 mod 32)
  int t = threadIdx.x, wg = blockIdx.x;
  long a0 = (long)wg * 64;
  int b0 = wg * 4;
  int lane = t & 63, w = t >> 6;           // w in 0..7
  int lrow = lane & 15, hi = lane >> 4;    // hi in 0..3
  int lk = hi * 8;

  // ---- LN1: wave w handles rows w*8 .. w*8+7
  {
    float4 gv1 = ((const float4*)g1)[lane];
    float4 bv1 = ((const float4*)be1)[lane];
#pragma unroll
    for (int rr = 0; rr < 8; ++rr) {
      int row = w * 8 + rr;
      float4 xv = ((const float4*)(x + (a0 + row) * 256))[lane];
      float4 uv = ((const float4*)(upd + (long)(b0 + (row >> 4)) * 256))[lane];
      float4 v;
      v.x = xv.x + uv.x; v.y = xv.y + uv.y; v.z = xv.z + uv.z; v.w = xv.w + uv.w;
      float s = v.x + v.y + v.z + v.w;
      float sq = v.x * v.x + v.y * v.y + v.z * v.z + v.w * v.w;
#pragma unroll
      for (int d = 1; d < 64; d <<= 1) { s += __shfl_xor(s, d); sq += __shfl_xor(sq, d); }
      float mu = s * (1.f / 256.f);
      float var = sq * (1.f / 256.f) - mu * mu;
      float rstd = rsqrtf(fmaxf(var, 0.f) + 1e-5f);
      uint2 q;
      q.x = cvt2((v.x - mu) * rstd * gv1.x + bv1.x, (v.y - mu) * rstd * gv1.y + bv1.y);
      q.y = cvt2((v.z - mu) * rstd * gv1.z + bv1.z, (v.w - mu) * rstd * gv1.w + bv1.w);
      *(uint2*)&x1s[row][lane * 4] = q;
    }
  }
  __syncthreads();

  floatx4 zero = {0.f, 0.f, 0.f, 0.f};
  floatx4 acc2[2][4];  // [cb][rb]: D[outcol][atom]
#pragma unroll
  for (int cb = 0; cb < 2; ++cb)
    for (int rb = 0; rb < 4; ++rb) acc2[cb][rb] = zero;

  for (int s = 0; s < 4; ++s) {
    // --- hoist GEMM1 weight frags: wave's 16 hidden cols, full K=256
    int hc = s * 128 + w * 16 + lrow;
    short8 wf[8];
#pragma unroll
    for (int k0 = 0; k0 < 8; ++k0)
      wf[k0] = *(const short8*)(W1t + hc * 256 + k0 * 32 + lk);
    // --- GEMM1: A=W1 (m=hid), B=x (n=atom) -> D[hid][atom]
    floatx4 acc1[4] = {zero, zero, zero, zero};
#pragma unroll
    for (int k0 = 0; k0 < 8; ++k0) {
      short8 af0 = *(const short8*)&x1s[0 + lrow][k0 * 32 + lk];
      short8 af1 = *(const short8*)&x1s[16 + lrow][k0 * 32 + lk];
      short8 af2 = *(const short8*)&x1s[32 + lrow][k0 * 32 + lk];
      short8 af3 = *(const short8*)&x1s[48 + lrow][k0 * 32 + lk];
      acc1[0] = __builtin_amdgcn_mfma_f32_16x16x32_bf16(wf[k0], af0, acc1[0], 0, 0, 0);
      acc1[1] = __builtin_amdgcn_mfma_f32_16x16x32_bf16(wf[k0], af1, acc1[1], 0, 0, 0);
      acc1[2] = __builtin_amdgcn_mfma_f32_16x16x32_bf16(wf[k0], af2, acc1[2], 0, 0, 0);
      acc1[3] = __builtin_amdgcn_mfma_f32_16x16x32_bf16(wf[k0], af3, acc1[3], 0, 0, 0);
    }
    // --- hoist GEMM2 weight frags (latency hides under barriers + hs writes)
    short8 wf2[8];
#pragma unroll
    for (int cb = 0; cb < 2; ++cb)
      for (int ks = 0; ks < 4; ++ks)
        wf2[cb * 4 + ks] = *(const short8*)(W2t + (w * 32 + cb * 16 + lrow) * 512 + s * 128 + ks * 32 + lk);
    // bias1 for hid = s*128 + w*16 + hi*4 + i
    float4 b4 = ((const float4*)b1)[s * 32 + w * 4 + hi];
    __syncthreads();  // previous GEMM2 finished reading hs
    // lane holds D[hid = w*16+hi*4+i][atom = rb*16+lrow] -> packed b64 store
#pragma unroll
    for (int rb = 0; rb < 4; ++rb) {
      float r0 = fmaxf(acc1[rb][0] + b4.x, 0.f);
      float r1 = fmaxf(acc1[rb][1] + b4.y, 0.f);
      float r2 = fmaxf(acc1[rb][2] + b4.z, 0.f);
      float r3 = fmaxf(acc1[rb][3] + b4.w, 0.f);
      uint2 q;
      q.x = cvt2(r0, r1);
      q.y = cvt2(r2, r3);
      *(uint2*)&hs[rb * 16 + lrow][w * 16 + hi * 4] = q;
    }
    __syncthreads();
    // --- GEMM2 partial: A=W2 (m=outcol), B=hs (n=atom), K-slice = this phase's 128
#pragma unroll
    for (int ks = 0; ks < 4; ++ks) {
      short8 a20 = *(const short8*)&hs[0 + lrow][ks * 32 + lk];
      short8 a21 = *(const short8*)&hs[16 + lrow][ks * 32 + lk];
      short8 a22 = *(const short8*)&hs[32 + lrow][ks * 32 + lk];
      short8 a23 = *(const short8*)&hs[48 + lrow][ks * 32 + lk];
#pragma unroll
      for (int cb = 0; cb < 2; ++cb) {
        acc2[cb][0] = __builtin_amdgcn_mfma_f32_16x16x32_bf16(wf2[cb * 4 + ks], a20, acc2[cb][0], 0, 0, 0);
        acc2[cb][1] = __builtin_amdgcn_mfma_f32_16x16x32_bf16(wf2[cb * 4 + ks], a21, acc2[cb][1], 0, 0, 0);
        acc2[cb][2] = __builtin_amdgcn_mfma_f32_16x16x32_bf16(wf2[cb * 4 + ks], a22, acc2[cb][2], 0, 0, 0);
        acc2[cb][3] = __builtin_amdgcn_mfma_f32_16x16x32_bf16(wf2[cb * 4 + ks], a23, acc2[cb][3], 0, 0, 0);
      }
    }
  }

  // epilogue: lane holds D[outcol = w*32+cb*16+hi*4+i][atom = rb*16+lrow]
  // residual (bf16 x1) + bias2, packed b64 RMW into x1s
#pragma unroll
  for (int cb = 0; cb < 2; ++cb) {
    float4 b4 = ((const float4*)b2)[w * 8 + cb * 4 + hi];
    int colb = w * 32 + cb * 16 + hi * 4;
#pragma unroll
    for (int rb = 0; rb < 4; ++rb) {
      int atom = rb * 16 + lrow;
      ushort4 old = *(const ushort4*)&x1s[atom][colb];
      float r0 = acc2[cb][rb][0] + b4.x + bfu2f(old.x);
      float r1 = acc2[cb][rb][1] + b4.y + bfu2f(old.y);
      float r2 = acc2[cb][rb][2] + b4.z + bfu2f(old.z);
      float r3 = acc2[cb][rb][3] + b4.w + bfu2f(old.w);
      uint2 q;
      q.x = cvt2(r0, r1);
      q.y = cvt2(r2, r3);
      *(uint2*)&x1s[atom][colb] = q;
    }
  }
  __syncthreads();

  // ---- LN2 + coalesced store: wave w handles rows w*8 .. w*8+7
  {
    float4 gv2 = ((const float4*)g2)[lane];
    float4 bv2 = ((const float4*)be2)[lane];
#pragma unroll
    for (int rr = 0; rr < 8; ++rr) {
      int row = w * 8 + rr;
      ushort4 u = *(const ushort4*)&x1s[row][lane * 4];
      float v0 = bfu2f(u.x), v1 = bfu2f(u.y), v2 = bfu2f(u.z), v3 = bfu2f(u.w);
      float s = v0 + v1 + v2 + v3;
      float sq = v0 * v0 + v1 * v1 + v2 * v2 + v3 * v3;
#pragma unroll
      for (int d = 1; d < 64; d <<= 1) { s += __shfl_xor(s, d); sq += __shfl_xor(sq, d); }
      float mu = s * (1.f / 256.f);
      float var = sq * (1.f / 256.f) - mu * mu;
      float rstd = rsqrtf(fmaxf(var, 0.f) + 1e-5f);
      float4 o;
      o.x = (v0 - mu) * rstd * gv2.x + bv2.x;
      o.y = (v1 - mu) * rstd * gv2.y + bv2.y;
      o.z = (v2 - mu) * rstd * gv2.z + bv2.z;
      o.w = (v3 - mu) * rstd * gv2.w + bv2.w;
      ((float4*)(out + (a0 + row) * 256))[lane] = o;
    }
  }
}

extern "C" void kernel_launch(void* const* d_in, const int* in_sizes, int n_in,
                              void* d_out, int out_size, void* d_ws, size_t ws_size,
                              hipStream_t stream) {
  (void)in_sizes; (void)n_in; (void)out_size; (void)ws_size;
  const float* x    = (const float*)d_in[0];
  const float* pos  = (const float*)d_in[1];
  const float* seed = (const float*)d_in[4];
  const float* Wq   = (const float*)d_in[5];
  const float* bq   = (const float*)d_in[6];
  const float* Wk   = (const float*)d_in[7];
  const float* bk   = (const float*)d_in[8];
  const float* Wv   = (const float*)d_in[9];
  const float* bv   = (const float*)d_in[10];
  const float* Wo   = (const float*)d_in[11];
  const float* bo   = (const float*)d_in[12];
  const float* centers = (const float*)d_in[13];
  const float* widths  = (const float*)d_in[14];
  const float* geom_w  = (const float*)d_in[15];
  const float* geom_b  = (const float*)d_in[16];
  const float* cq_w = (const float*)d_in[17];
  const float* cq_b = (const float*)d_in[18];
  const float* ck_w = (const float*)d_in[19];
  const float* ck_b = (const float*)d_in[20];
  const float* cv_w = (const float*)d_in[21];
  const float* cv_b = (const float*)d_in[22];
  const float* w1m  = (const float*)d_in[23];
  const float* b1m  = (const float*)d_in[24];
  const float* w2m  = (const float*)d_in[25];
  const float* b2m  = (const float*)d_in[26];
  const float* fw1  = (const float*)d_in[27];
  const float* fb1  = (const float*)d_in[28];
  const float* fw2  = (const float*)d_in[29];
  const float* fb2  = (const float*)d_in[30];
  const float* g1   = (const float*)d_in[31];
  const float* be1  = (const float*)d_in[32];
  const float* g2   = (const float*)d_in[33];
  const float* be2  = (const float*)d_in[34];

  float* ws = (float*)d_ws;
  float* sb = ws + 0;                                       // 64
  unsigned short* A_bfT = (unsigned short*)(ws + 64);       // 16*256 bf16 -> ends 2112
  float* M     = ws + 2112;     // 256*336 = 86016 -> ends 88128
  float* vbias = ws + 88128;    // 352 -> ends 88480
  unsigned short* MMTb = (unsigned short*)(ws + 88480);     // 336*256 bf16 = 43008 floats -> ends 131488
  float* vb2   = ws + 131488;   // 352 -> ends 131840
  unsigned short* CV1Tb = (unsigned short*)(ws + 131840);   // 256*320 bf16 = 40960 floats -> ends 172800
  float* cb1   = ws + 172800;   // 256 -> ends 173056
  unsigned short* W1t = (unsigned short*)(ws + 173056);     // 512*256 bf16 = 65536 floats -> ends 238592
  unsigned short* W2t = (unsigned short*)(ws + 238592);     // 256*512 bf16 = 65536 floats -> ends 304128
  unsigned short* W2mTb = (unsigned short*)(ws + 304128);   // 256*256 bf16 = 32768 floats -> ends 336896
  unsigned short* WvTb = (unsigned short*)(ws + 336896);    // 256*256 bf16 = 32768 floats -> ends 369664
  float* updw = ws + 369664;                                // 8192*256 f32 -> ends 2466816
  unsigned short* geomT = (unsigned short*)(ws + 2466816);  // 64*32 bf16
  // total ws use: ~10 MB

  // scratch inside d_out (134 MB, fully overwritten by kf at the end):
  float* outp = (float*)d_out;
  unsigned short* zbf = (unsigned short*)(outp + 21626880); // 8192*320 bf16 = 5.24 MB

  prepA<<<dim3(1867), dim3(352), 0, stream>>>(seed, Wq, bq, Wk, bk, A_bfT, sb,
      cq_w, cq_b, ck_w, ck_b, M, vbias,
      cv_w, cv_b, w1m, b1m, CV1Tb, cb1,
      fw1, fw2, w2m, geom_w, W1t, W2t, W2mTb, geomT, Wv, WvTb);
  kp2<<<dim3(257), dim3(352), 0, stream>>>(Wo, bo, M, vbias, MMTb, vb2);
  kgm3<<<dim3(2048), dim3(256), 0, stream>>>(x, pos, A_bfT, sb, WvTb, bv, MMTb, vb2,
      centers, widths, geomT, geom_b, zbf);
  gb2<<<dim3(512), dim3(256), 0, stream>>>(zbf, CV1Tb, cb1, W2mTb, b2m, updw);
  kf<<<dim3(2048), dim3(512), 0, stream>>>(x, updw, W1t, W2t, fb1, fb2, g1, be1, g2, be2, outp);
}

// Round 18
// 319.641 us; speedup vs baseline: 1.0161x; 1.0131x over previous
//
#include <hip/hip_runtime.h>
#include <hip/hip_bf16.h>

// Sizes (fixed by the problem)
#define NATOMS 131072
#define NBLK   8192
#define HDIM   256
#define NHEAD  8
#define TDIM   336   // 320 aug dims + 1 (ck_b . Q) + pad

typedef __attribute__((ext_vector_type(8))) short short8;
typedef __attribute__((ext_vector_type(4))) float floatx4;

__device__ __forceinline__ float bfu2f(unsigned short u) {
  unsigned int v = ((unsigned int)u) << 16;
  return __builtin_bit_cast(float, v);
}
__device__ __forceinline__ unsigned short f2bfu(float f) {
  unsigned int u = __builtin_bit_cast(unsigned int, f);
  u += 0x7fffu + ((u >> 16) & 1u);
  return (unsigned short)(u >> 16);
}
// packs bf16(a) into low 16, bf16(b) into high 16 (RNE)
__device__ __forceinline__ unsigned int cvt2(float a, float b) {
  unsigned int r;
  asm("v_cvt_pk_bf16_f32 %0, %1, %2" : "=v"(r) : "v"(a), "v"(b));
  return r;
}

// ---------------- prepA: fused independent preps.
// b in [0,9): k0_prep ; [9,265): kp1 ; [265,586): kp3 (-> CV1Tb bf16 transposed) ;
// [586,1611): kcast {W1t, W2t, geomT, W2mTb} ; [1611,1867): WvTb.
__global__ __launch_bounds__(352) void prepA(
    const float* __restrict__ seed, const float* __restrict__ Wq,
    const float* __restrict__ bq, const float* __restrict__ Wk,
    const float* __restrict__ bk, unsigned short* __restrict__ A_bfT,
    float* __restrict__ sb,
    const float* __restrict__ cq_w, const float* __restrict__ cq_b,
    const float* __restrict__ ck_w, const float* __restrict__ ck_b,
    float* __restrict__ M, float* __restrict__ vbias,
    const float* __restrict__ cv_w, const float* __restrict__ cv_b,
    const float* __restrict__ w1m, const float* __restrict__ b1m,
    unsigned short* __restrict__ CV1Tb, float* __restrict__ cb1,
    const float* __restrict__ fw1, const float* __restrict__ fw2,
    const float* __restrict__ w2m, const float* __restrict__ geom_w,
    unsigned short* __restrict__ W1t, unsigned short* __restrict__ W2t,
    unsigned short* __restrict__ W2mTb, unsigned short* __restrict__ geomT,
    const float* __restrict__ Wv, unsigned short* __restrict__ WvTb) {
  __shared__ float row[256];
  int t = threadIdx.x, b = blockIdx.x;
  if (b < 9) {
    // ---- k0: q = seed@Wq+bq ; A_bfT ; sb
    if (t < 256) {
      float acc = bq[t];
      for (int c = 0; c < 256; ++c) acc += seed[c] * Wq[c * 256 + t];
      row[t] = acc;
    }
    __syncthreads();
    const float scale = 0.17677669529663687f;  // 1/sqrt(32)
    if (b < 8) {
      if (t < 256) {
        int o = b * 256 + t;
        int c = o >> 3, h = o & 7;
        float a = 0.f;
        for (int d = 0; d < 32; ++d) a += Wk[c * 256 + h * 32 + d] * row[h * 32 + d];
        A_bfT[h * 256 + c] = f2bfu(a * scale);
      }
    } else {
      if (t < 8) {
        float a = 0.f;
        for (int d = 0; d < 32; ++d) a += bk[t * 32 + d] * row[t * 32 + d];
        sb[t] = a * scale;
      }
      if (t < 256)
        for (int idx = t; idx < 2048; idx += 256) A_bfT[2048 + idx] = 0;
    }
  } else if (b < 265) {
    // ---- kp1: M[i][c] = cq_w[i,:] . ckT[:,c]
    int i = b - 9;
    if (t < 256) row[t] = cq_w[i * 256 + t];
    __syncthreads();
    if (t < TDIM) {
      float a = 0.f;
      if (t < 320) { const float* w = ck_w + t * 256; for (int j = 0; j < 256; ++j) a += row[j] * w[j]; }
      else if (t == 320) { for (int j = 0; j < 256; ++j) a += row[j] * ck_b[j]; }
      M[i * TDIM + t] = a;
    }
    if (i == 0) {
      __syncthreads();
      if (t < 256) row[t] = cq_b[t];
      __syncthreads();
      if (t < TDIM) {
        float a = 0.f;
        if (t < 320) { const float* w = ck_w + t * 256; for (int j = 0; j < 256; ++j) a += row[j] * w[j]; }
        else if (t == 320) { for (int j = 0; j < 256; ++j) a += row[j] * ck_b[j]; }
        vbias[t] = a;
      }
    }
  } else if (b < 586) {
    // ---- kp3: CV1Tb[j][k] = bf16(cv_w[k,:] . w1m[:,j]) ; block 320: cb1 f32
    int k = b - 265;
    if (t < 256) row[t] = (k < 320) ? cv_w[k * 256 + t] : cv_b[t];
    __syncthreads();
    if (t < 256) {
      float a = 0.f;
      for (int i = 0; i < 256; ++i) a += row[i] * w1m[i * 256 + t];
      if (k < 320) CV1Tb[t * 320 + k] = f2bfu(a);
      else cb1[t] = a + b1m[t];
    }
  } else if (b < 1611) {
    // ---- kcast
    int bb = b - 586;
    if (bb < 512) {
      if (t < 256) W1t[bb * 256 + t] = f2bfu(fw1[t * 512 + bb]);
    } else if (bb < 768) {
      int n = bb - 512;
      if (t < 256)
        for (int m = 0; m < 2; ++m) {
          int k = t + 256 * m;
          W2t[n * 512 + k] = f2bfu(fw2[k * 256 + n]);
        }
    } else if (bb == 768) {
      if (t < 256)
        for (int idx = t; idx < 2048; idx += 256) {
          int q = idx >> 5, r = idx & 31;
          geomT[idx] = (r < 16) ? f2bfu(geom_w[r * 64 + q]) : (unsigned short)0;
        }
    } else {
      int n = bb - 769;
      if (t < 256) W2mTb[n * 256 + t] = f2bfu(w2m[t * 256 + n]);
    }
  } else {
    // ---- WvTb[j][c] = bf16(Wv[c][j])
    int j = b - 1611;
    if (t < 256) WvTb[j * 256 + t] = f2bfu(Wv[t * 256 + j]);
  }
}

// ---------------- Kp2: MMTb[c][p] = bf16(Wo[p,:] . M[:,c]) ; block 256: vb2[c] = bo.M[:,c] + vbias[c]
__global__ __launch_bounds__(352) void kp2(const float* __restrict__ Wo,
    const float* __restrict__ bo, const float* __restrict__ M,
    const float* __restrict__ vbias, unsigned short* __restrict__ MMTb,
    float* __restrict__ vb2) {
  __shared__ float row[256];
  int p = blockIdx.x, t = threadIdx.x;
  const float* src = (p < 256) ? (Wo + p * 256) : bo;
  if (t < 256) row[t] = src[t];
  __syncthreads();
  if (t < TDIM) {
    float a = 0.f;
    for (int i = 0; i < 256; ++i) a += row[i] * M[i * TDIM + t];
    if (p < 256) MMTb[t * 256 + p] = f2bfu(a);
    else vb2[t] = a + vbias[t];
  }
}

// ---------------- KGM3 (round-15 layout): fused kgm + kg3, all heavy phases MFMA.
// Per wg: 64 atoms = 4 blocks. x read ONCE; T lives only in LDS; z written bf16.
// Phases: load -> cent -> {rbfl, S} -> Y -> BP -> {rbfp, T} -> scores -> z.
__global__ __launch_bounds__(256) void kgm3(const float* __restrict__ x,
    const float* __restrict__ pos,
    const unsigned short* __restrict__ A_bfT, const float* __restrict__ sb,
    const unsigned short* __restrict__ WvTb, const float* __restrict__ bv,
    const unsigned short* __restrict__ MMTb, const float* __restrict__ vb2,
    const float* __restrict__ centers, const float* __restrict__ widths,
    const unsigned short* __restrict__ geomT, const float* __restrict__ geom_b,
    unsigned short* __restrict__ zbf) {
  __shared__ unsigned short xs[64][264];            // persists through z phase
  __shared__ __align__(16) char r2[16896];          // ysb -> rbfpb
  unsigned short (*ysb)[8][264] = (unsigned short(*)[8][264])r2;   // 16896 B
  unsigned short (*rbfpb)[72] = (unsigned short(*)[72])r2;         // 9216 B
  __shared__ unsigned short rbflb[64][32];
  __shared__ unsigned short bpb[4][264];
  __shared__ unsigned short TbfT[4][328];
  __shared__ float Tbias[4];
  __shared__ unsigned short wsm[64][8];
  __shared__ float ps[64][3];
  __shared__ float cent[4][3];
  __shared__ float ctr[16], wid[16];
  __shared__ float w2l[64];

  int t = threadIdx.x, wg = blockIdx.x;
  long a0 = (long)wg * 64;
  int b0 = wg * 4;
  int lane = t & 63, w = t >> 6;
  int lrow = lane & 15, hi = lane >> 4, lk = hi * 8;
  floatx4 zero = {0.f, 0.f, 0.f, 0.f};

  // ---- load x -> xs (bf16), pos/centers/widths
  const float4* x4 = (const float4*)(x + a0 * 256);
  for (int m = 0; m < 16; ++m) {
    int f4 = t + 256 * m;
    int row = f4 >> 6, c4 = f4 & 63;
    float4 v = x4[f4];
    uint2 q;
    q.x = cvt2(v.x, v.y);
    q.y = cvt2(v.z, v.w);
    *(uint2*)&xs[row][c4 * 4] = q;
  }
  if (t < 192) ps[t / 3][t % 3] = pos[a0 * 3 + t];
  if (t >= 224 && t < 240) ctr[t - 224] = centers[t - 224];
  if (t >= 240) wid[t - 240] = widths[t - 240];
  float sblv = (lrow < 8) ? sb[lrow] : 0.f;
  __syncthreads();                                   // B1

  if (t < 12) {
    int b = t / 3, d = t % 3;
    float s = 0.f;
    for (int i = 0; i < 16; ++i) s += ps[b * 16 + i][d];
    cent[b][d] = s * 0.0625f;
  }
  __syncthreads();                                   // B2

  // ---- rbfl (bf16, k padded to 32)
  if (t < 64) {
    int b = t >> 4;
    float dx = ps[t][0] - cent[b][0];
    float dy = ps[t][1] - cent[b][1];
    float dz = ps[t][2] - cent[b][2];
    float dist = sqrtf(dx * dx + dy * dy + dz * dz);
    for (int r = 0; r < 16; ++r) {
      float dd = dist - ctr[r];
      rbflb[t][r] = f2bfu(__expf(-dd * dd / (2.f * wid[r] * wid[r])));
      rbflb[t][16 + r] = 0;
    }
  }

  // ---- Phase S: PMA scores for atile w + per-block softmax -> wsm
  {
    floatx4 accs = zero;
#pragma unroll
    for (int k0 = 0; k0 < 8; ++k0) {
      short8 af = *(const short8*)&xs[16 * w + lrow][k0 * 32 + lk];
      short8 bf = *(const short8*)(A_bfT + lrow * 256 + k0 * 32 + lk);
      accs = __builtin_amdgcn_mfma_f32_16x16x32_bf16(af, bf, accs, 0, 0, 0);
    }
    float sv[4], e[4];
    float mx = -1e30f;
#pragma unroll
    for (int i = 0; i < 4; ++i) { sv[i] = accs[i] + sblv; mx = fmaxf(mx, sv[i]); }
    mx = fmaxf(mx, __shfl_xor(mx, 16));
    mx = fmaxf(mx, __shfl_xor(mx, 32));
    float se = 0.f;
#pragma unroll
    for (int i = 0; i < 4; ++i) { e[i] = __expf(sv[i] - mx); se += e[i]; }
    se += __shfl_xor(se, 16);
    se += __shfl_xor(se, 32);
    float inv = 1.f / fmaxf(se, 1e-20f);
    if (lrow < 8) {
#pragma unroll
      for (int i = 0; i < 4; ++i) wsm[16 * w + hi * 4 + i][lrow] = f2bfu(e[i] * inv);
    }
  }
  __syncthreads();                                   // B3

  // ---- Phase Y: pooled y via zero-masked K=32 MFMAs -> ysb (bf16)
  {
    int h = lrow & 7, bsel = lrow >> 3;
    short8 A1, A2;
#pragma unroll
    for (int j = 0; j < 8; ++j) {
      int atom = 8 * hi + j;
      unsigned short w1v = wsm[atom][h];
      unsigned short w2v = wsm[32 + atom][h];
      A1[j] = (bsel == (atom >> 4)) ? (short)w1v : (short)0;
      A2[j] = (bsel == (atom >> 4)) ? (short)w2v : (short)0;
    }
#pragma unroll
    for (int q = 0; q < 4; ++q) {
      int ct = 4 * w + q;
      int cb = ct * 16 + lrow;
      short8 B1, B2;
#pragma unroll
      for (int j = 0; j < 8; ++j) {
        B1[j] = (short)xs[8 * hi + j][cb];
        B2[j] = (short)xs[32 + 8 * hi + j][cb];
      }
      floatx4 d1 = __builtin_amdgcn_mfma_f32_16x16x32_bf16(A1, B1, zero, 0, 0, 0);
      floatx4 d2 = __builtin_amdgcn_mfma_f32_16x16x32_bf16(A2, B2, zero, 0, 0, 0);
#pragma unroll
      for (int i = 0; i < 4; ++i) {
        int r = hi * 4 + i;
        int hh = r & 7, bb = r >> 3;
        ysb[bb][hh][ct * 16 + lrow] = f2bfu(d1[i]);
        ysb[2 + bb][hh][ct * 16 + lrow] = f2bfu(d2[i]);
      }
    }
  }
  __syncthreads();                                   // B4

  // ---- BP via MFMA: D[block][j] = y[block][h][:] . WvT[j][:]. Wave w: heads 2w, 2w+1.
#pragma unroll
  for (int hh2 = 0; hh2 < 2; ++hh2) {
    int hd = 2 * w + hh2;
#pragma unroll
    for (int n = 0; n < 2; ++n) {
      floatx4 acc = zero;
#pragma unroll
      for (int ks = 0; ks < 8; ++ks) {
        short8 A = *(const short8*)&ysb[lrow & 3][hd][ks * 32 + lk];
        short8 B = *(const short8*)(WvTb + (hd * 32 + n * 16 + lrow) * 256 + ks * 32 + lk);
        acc = __builtin_amdgcn_mfma_f32_16x16x32_bf16(A, B, acc, 0, 0, 0);
      }
      if (hi == 0) {
        int col = hd * 32 + n * 16 + lrow;
        float bvc = bv[col];
#pragma unroll
        for (int i = 0; i < 4; ++i)
          bpb[i][col] = f2bfu(acc[i] + bvc);
      }
    }
  }
  __syncthreads();                                   // B5 (ysb dead)

  // ---- rbfp = rbfl @ geomT^T + geom_b via MFMA -> rbfpb (aliases ysb region)
  {
    short8 A = *(const short8*)&rbflb[16 * w + lrow][lk];
#pragma unroll
    for (int qt = 0; qt < 4; ++qt) {
      short8 B = *(const short8*)(geomT + (qt * 16 + lrow) * 32 + lk);
      floatx4 d = __builtin_amdgcn_mfma_f32_16x16x32_bf16(A, B, zero, 0, 0, 0);
      float gb = geom_b[qt * 16 + lrow];
#pragma unroll
      for (int i = 0; i < 4; ++i)
        rbfpb[16 * w + hi * 4 + i][qt * 16 + lrow] = f2bfu(d[i] + gb);
    }
  }
  // ---- T via MFMA: T[block][c] = bp[block][:] . MMT[c][:] + vb2[c] -> TbfT (LDS)
  for (int ct = w; ct < 21; ct += 4) {
    floatx4 acc = zero;
#pragma unroll
    for (int ks = 0; ks < 8; ++ks) {
      short8 A = *(const short8*)&bpb[lrow & 3][ks * 32 + lk];
      short8 B = *(const short8*)(MMTb + (ct * 16 + lrow) * 256 + ks * 32 + lk);
      acc = __builtin_amdgcn_mfma_f32_16x16x32_bf16(A, B, acc, 0, 0, 0);
    }
    if (hi == 0) {
      int c = ct * 16 + lrow;
      if (c <= 320) {
        float vb = vb2[c];
        if (c < 320) {
#pragma unroll
          for (int i = 0; i < 4; ++i) TbfT[i][c] = f2bfu(acc[i] + vb);
        } else {
#pragma unroll
          for (int i = 0; i < 4; ++i) Tbias[i] = acc[i] + vb;
        }
      }
    }
  }
  __syncthreads();                                   // B6

  // ---- cross-attn scores: D[atom][j] = Xaug[atom,:] . T[j,:] (col j==w used)
  {
    floatx4 acc = zero;
#pragma unroll
    for (int k0 = 0; k0 < 8; ++k0) {
      short8 af = *(const short8*)&xs[16 * w + lrow][k0 * 32 + lk];
      short8 bf = *(const short8*)&TbfT[lrow & 3][k0 * 32 + lk];
      acc = __builtin_amdgcn_mfma_f32_16x16x32_bf16(af, bf, acc, 0, 0, 0);
    }
#pragma unroll
    for (int kq = 0; kq < 2; ++kq) {
      short8 af = *(const short8*)&rbfpb[16 * w + lrow][kq * 32 + lk];
      short8 bf = *(const short8*)&TbfT[lrow & 3][256 + kq * 32 + lk];
      acc = __builtin_amdgcn_mfma_f32_16x16x32_bf16(af, bf, acc, 0, 0, 0);
    }
    float tb = Tbias[w];
    float sv[4], e[4];
    float mx = -1e30f;
#pragma unroll
    for (int i = 0; i < 4; ++i) { sv[i] = (acc[i] + tb) * 0.0625f; mx = fmaxf(mx, sv[i]); }
    mx = fmaxf(mx, __shfl_xor(mx, 16));
    mx = fmaxf(mx, __shfl_xor(mx, 32));
    float se = 0.f;
#pragma unroll
    for (int i = 0; i < 4; ++i) { e[i] = __expf(sv[i] - mx); se += e[i]; }
    se += __shfl_xor(se, 16);
    se += __shfl_xor(se, 32);
    float inv = 1.f / fmaxf(se, 1e-20f);
    if (lrow == w) {
#pragma unroll
      for (int i = 0; i < 4; ++i) w2l[16 * w + hi * 4 + i] = e[i] * inv;
    }
  }
  __syncthreads();                                   // B7

  // ---- z: weighted pooling (f32 accum) -> zbf (bf16; gb2 rounded to bf16 anyway)
  for (int b = 0; b < 4; ++b) {
    float zv = 0.f;
    for (int i = 0; i < 16; ++i) zv += w2l[b * 16 + i] * bfu2f(xs[b * 16 + i][t]);
    zbf[(long)(b0 + b) * 320 + t] = f2bfu(zv);
  }
  {
    int q = t & 63, b = t >> 6;
    float zq = 0.f;
    for (int i = 0; i < 16; ++i) zq += w2l[b * 16 + i] * bfu2f(rbfpb[b * 16 + i][q]);
    zbf[(long)(b0 + b) * 320 + 256 + q] = f2bfu(zq);
  }
}

// ---------------- Gb2 v4 (MFMA, bf16 z input): upd = relu(z@CV1+cb1)@cmlp_w2 + cmlp_b2
// 16 blocks / wg. M=16(blocks) x N=256 x K=320/256 via 16x16x32 bf16 MFMA.
__global__ __launch_bounds__(256, 4) void gb2(const unsigned short* __restrict__ zbf,
    const unsigned short* __restrict__ CV1Tb, const float* __restrict__ cb1,
    const unsigned short* __restrict__ W2mTb, const float* __restrict__ b2m,
    float* __restrict__ upd) {
  __shared__ unsigned short zb[16][328];   // 656B stride (164 dw = 4 mod 32)
  __shared__ unsigned short prb[16][264];  // 528B stride
  int t = threadIdx.x;
  int B0 = blockIdx.x * 16;
  int lane = t & 63, w = t >> 6;
  int lrow = lane & 15, hi = lane >> 4, lk = hi * 8;
  floatx4 zero = {0.f, 0.f, 0.f, 0.f};

  for (int idx = t; idx < 16 * 160; idx += 256) {
    int e = idx * 2;
    int r = e / 320, c = e - r * 320;
    *(ushort2*)&zb[r][c] = *(const ushort2*)(zbf + (long)(B0 + r) * 320 + c);
  }
  __syncthreads();

  // GEMM1 + relu -> prb (bf16). Wave w owns out-col tiles w*4 .. w*4+3.
#pragma unroll
  for (int tt = 0; tt < 4; ++tt) {
    int colt = w * 4 + tt;
    floatx4 acc = zero;
    const unsigned short* ap = CV1Tb + (colt * 16 + lrow) * 320 + lk;
#pragma unroll
    for (int ks = 0; ks < 10; ++ks) {
      short8 A = *(const short8*)(ap + ks * 32);
      short8 B = *(const short8*)&zb[lrow][ks * 32 + lk];
      acc = __builtin_amdgcn_mfma_f32_16x16x32_bf16(A, B, acc, 0, 0, 0);
    }
    float4 cbv = ((const float4*)cb1)[colt * 4 + hi];
    float r0 = fmaxf(acc[0] + cbv.x, 0.f);
    float r1 = fmaxf(acc[1] + cbv.y, 0.f);
    float r2 = fmaxf(acc[2] + cbv.z, 0.f);
    float r3 = fmaxf(acc[3] + cbv.w, 0.f);
    uint2 q;
    q.x = cvt2(r0, r1);
    q.y = cvt2(r2, r3);
    *(uint2*)&prb[lrow][colt * 16 + hi * 4] = q;
  }
  __syncthreads();

  // GEMM2 -> upd (f32, float4 stores)
#pragma unroll
  for (int tt = 0; tt < 4; ++tt) {
    int colt = w * 4 + tt;
    floatx4 acc = zero;
    const unsigned short* ap = W2mTb + (colt * 16 + lrow) * 256 + lk;
#pragma unroll
    for (int ks = 0; ks < 8; ++ks) {
      short8 A = *(const short8*)(ap + ks * 32);
      short8 B = *(const short8*)&prb[lrow][ks * 32 + lk];
      acc = __builtin_amdgcn_mfma_f32_16x16x32_bf16(A, B, acc, 0, 0, 0);
    }
    float4 b2v = ((const float4*)b2m)[colt * 4 + hi];
    float4 st;
    st.x = acc[0] + b2v.x;
    st.y = acc[1] + b2v.y;
    st.z = acc[2] + b2v.z;
    st.w = acc[3] + b2v.w;
    *(float4*)&upd[(long)(B0 + lrow) * 256 + colt * 16 + hi * 4] = st;
  }
}

// ---------------- KF v5: same structure as v4, launch_bounds(512,2) to unpin VGPR
// so the hoisted wf/wf2 weight fragments actually stay resident.
__global__ __launch_bounds__(512, 2) void kf(const float* __restrict__ x,
    const float* __restrict__ upd, const unsigned short* __restrict__ W1t,
    const unsigned short* __restrict__ W2t, const float* __restrict__ b1,
    const float* __restrict__ b2, const float* __restrict__ g1,
    const float* __restrict__ be1, const float* __restrict__ g2,
    const float* __restrict__ be2, float* __restrict__ out) {
  __shared__ unsigned short x1s[64][264];  // post-LN1 (bf16), stride 528B (132 dw ≡ 4 mod 32)
  __shared__ unsigned short hs[64][136];   // 128-wide hidden slice, stride 272B (68 dw ≡ 4 mod 32)
  int t = threadIdx.x, wg = blockIdx.x;
  long a0 = (long)wg * 64;
  int b0 = wg * 4;
  int lane = t & 63, w = t >> 6;           // w in 0..7
  int lrow = lane & 15, hi = lane >> 4;    // hi in 0..3
  int lk = hi * 8;

  // ---- LN1: wave w handles rows w*8 .. w*8+7
  {
    float4 gv1 = ((const float4*)g1)[lane];
    float4 bv1 = ((const float4*)be1)[lane];
#pragma unroll
    for (int rr = 0; rr < 8; ++rr) {
      int row = w * 8 + rr;
      float4 xv = ((const float4*)(x + (a0 + row) * 256))[lane];
      float4 uv = ((const float4*)(upd + (long)(b0 + (row >> 4)) * 256))[lane];
      float4 v;
      v.x = xv.x + uv.x; v.y = xv.y + uv.y; v.z = xv.z + uv.z; v.w = xv.w + uv.w;
      float s = v.x + v.y + v.z + v.w;
      float sq = v.x * v.x + v.y * v.y + v.z * v.z + v.w * v.w;
#pragma unroll
      for (int d = 1; d < 64; d <<= 1) { s += __shfl_xor(s, d); sq += __shfl_xor(sq, d); }
      float mu = s * (1.f / 256.f);
      float var = sq * (1.f / 256.f) - mu * mu;
      float rstd = rsqrtf(fmaxf(var, 0.f) + 1e-5f);
      uint2 q;
      q.x = cvt2((v.x - mu) * rstd * gv1.x + bv1.x, (v.y - mu) * rstd * gv1.y + bv1.y);
      q.y = cvt2((v.z - mu) * rstd * gv1.z + bv1.z, (v.w - mu) * rstd * gv1.w + bv1.w);
      *(uint2*)&x1s[row][lane * 4] = q;
    }
  }
  __syncthreads();

  floatx4 zero = {0.f, 0.f, 0.f, 0.f};
  floatx4 acc2[2][4];  // [cb][rb]: D[outcol][atom]
#pragma unroll
  for (int cb = 0; cb < 2; ++cb)
    for (int rb = 0; rb < 4; ++rb) acc2[cb][rb] = zero;

  for (int s = 0; s < 4; ++s) {
    // --- hoist GEMM1 weight frags: wave's 16 hidden cols, full K=256
    int hc = s * 128 + w * 16 + lrow;
    short8 wf[8];
#pragma unroll
    for (int k0 = 0; k0 < 8; ++k0)
      wf[k0] = *(const short8*)(W1t + hc * 256 + k0 * 32 + lk);
    // --- GEMM1: A=W1 (m=hid), B=x (n=atom) -> D[hid][atom]
    floatx4 acc1[4] = {zero, zero, zero, zero};
#pragma unroll
    for (int k0 = 0; k0 < 8; ++k0) {
      short8 af0 = *(const short8*)&x1s[0 + lrow][k0 * 32 + lk];
      short8 af1 = *(const short8*)&x1s[16 + lrow][k0 * 32 + lk];
      short8 af2 = *(const short8*)&x1s[32 + lrow][k0 * 32 + lk];
      short8 af3 = *(const short8*)&x1s[48 + lrow][k0 * 32 + lk];
      acc1[0] = __builtin_amdgcn_mfma_f32_16x16x32_bf16(wf[k0], af0, acc1[0], 0, 0, 0);
      acc1[1] = __builtin_amdgcn_mfma_f32_16x16x32_bf16(wf[k0], af1, acc1[1], 0, 0, 0);
      acc1[2] = __builtin_amdgcn_mfma_f32_16x16x32_bf16(wf[k0], af2, acc1[2], 0, 0, 0);
      acc1[3] = __builtin_amdgcn_mfma_f32_16x16x32_bf16(wf[k0], af3, acc1[3], 0, 0, 0);
    }
    // --- hoist GEMM2 weight frags (latency hides under barriers + hs writes)
    short8 wf2[8];
#pragma unroll
    for (int cb = 0; cb < 2; ++cb)
      for (int ks = 0; ks < 4; ++ks)
        wf2[cb * 4 + ks] = *(const short8*)(W2t + (w * 32 + cb * 16 + lrow) * 512 + s * 128 + ks * 32 + lk);
    // bias1 for hid = s*128 + w*16 + hi*4 + i
    float4 b4 = ((const float4*)b1)[s * 32 + w * 4 + hi];
    __syncthreads();  // previous GEMM2 finished reading hs
    // lane holds D[hid = w*16+hi*4+i][atom = rb*16+lrow] -> packed b64 store
#pragma unroll
    for (int rb = 0; rb < 4; ++rb) {
      float r0 = fmaxf(acc1[rb][0] + b4.x, 0.f);
      float r1 = fmaxf(acc1[rb][1] + b4.y, 0.f);
      float r2 = fmaxf(acc1[rb][2] + b4.z, 0.f);
      float r3 = fmaxf(acc1[rb][3] + b4.w, 0.f);
      uint2 q;
      q.x = cvt2(r0, r1);
      q.y = cvt2(r2, r3);
      *(uint2*)&hs[rb * 16 + lrow][w * 16 + hi * 4] = q;
    }
    __syncthreads();
    // --- GEMM2 partial: A=W2 (m=outcol), B=hs (n=atom), K-slice = this phase's 128
#pragma unroll
    for (int ks = 0; ks < 4; ++ks) {
      short8 a20 = *(const short8*)&hs[0 + lrow][ks * 32 + lk];
      short8 a21 = *(const short8*)&hs[16 + lrow][ks * 32 + lk];
      short8 a22 = *(const short8*)&hs[32 + lrow][ks * 32 + lk];
      short8 a23 = *(const short8*)&hs[48 + lrow][ks * 32 + lk];
#pragma unroll
      for (int cb = 0; cb < 2; ++cb) {
        acc2[cb][0] = __builtin_amdgcn_mfma_f32_16x16x32_bf16(wf2[cb * 4 + ks], a20, acc2[cb][0], 0, 0, 0);
        acc2[cb][1] = __builtin_amdgcn_mfma_f32_16x16x32_bf16(wf2[cb * 4 + ks], a21, acc2[cb][1], 0, 0, 0);
        acc2[cb][2] = __builtin_amdgcn_mfma_f32_16x16x32_bf16(wf2[cb * 4 + ks], a22, acc2[cb][2], 0, 0, 0);
        acc2[cb][3] = __builtin_amdgcn_mfma_f32_16x16x32_bf16(wf2[cb * 4 + ks], a23, acc2[cb][3], 0, 0, 0);
      }
    }
  }

  // epilogue: lane holds D[outcol = w*32+cb*16+hi*4+i][atom = rb*16+lrow]
  // residual (bf16 x1) + bias2, packed b64 RMW into x1s
#pragma unroll
  for (int cb = 0; cb < 2; ++cb) {
    float4 b4 = ((const float4*)b2)[w * 8 + cb * 4 + hi];
    int colb = w * 32 + cb * 16 + hi * 4;
#pragma unroll
    for (int rb = 0; rb < 4; ++rb) {
      int atom = rb * 16 + lrow;
      ushort4 old = *(const ushort4*)&x1s[atom][colb];
      float r0 = acc2[cb][rb][0] + b4.x + bfu2f(old.x);
      float r1 = acc2[cb][rb][1] + b4.y + bfu2f(old.y);
      float r2 = acc2[cb][rb][2] + b4.z + bfu2f(old.z);
      float r3 = acc2[cb][rb][3] + b4.w + bfu2f(old.w);
      uint2 q;
      q.x = cvt2(r0, r1);
      q.y = cvt2(r2, r3);
      *(uint2*)&x1s[atom][colb] = q;
    }
  }
  __syncthreads();

  // ---- LN2 + coalesced store: wave w handles rows w*8 .. w*8+7
  {
    float4 gv2 = ((const float4*)g2)[lane];
    float4 bv2 = ((const float4*)be2)[lane];
#pragma unroll
    for (int rr = 0; rr < 8; ++rr) {
      int row = w * 8 + rr;
      ushort4 u = *(const ushort4*)&x1s[row][lane * 4];
      float v0 = bfu2f(u.x), v1 = bfu2f(u.y), v2 = bfu2f(u.z), v3 = bfu2f(u.w);
      float s = v0 + v1 + v2 + v3;
      float sq = v0 * v0 + v1 * v1 + v2 * v2 + v3 * v3;
#pragma unroll
      for (int d = 1; d < 64; d <<= 1) { s += __shfl_xor(s, d); sq += __shfl_xor(sq, d); }
      float mu = s * (1.f / 256.f);
      float var = sq * (1.f / 256.f) - mu * mu;
      float rstd = rsqrtf(fmaxf(var, 0.f) + 1e-5f);
      float4 o;
      o.x = (v0 - mu) * rstd * gv2.x + bv2.x;
      o.y = (v1 - mu) * rstd * gv2.y + bv2.y;
      o.z = (v2 - mu) * rstd * gv2.z + bv2.z;
      o.w = (v3 - mu) * rstd * gv2.w + bv2.w;
      ((float4*)(out + (a0 + row) * 256))[lane] = o;
    }
  }
}

extern "C" void kernel_launch(void* const* d_in, const int* in_sizes, int n_in,
                              void* d_out, int out_size, void* d_ws, size_t ws_size,
                              hipStream_t stream) {
  (void)in_sizes; (void)n_in; (void)out_size; (void)ws_size;
  const float* x    = (const float*)d_in[0];
  const float* pos  = (const float*)d_in[1];
  const float* seed = (const float*)d_in[4];
  const float* Wq   = (const float*)d_in[5];
  const float* bq   = (const float*)d_in[6];
  const float* Wk   = (const float*)d_in[7];
  const float* bk   = (const float*)d_in[8];
  const float* Wv   = (const float*)d_in[9];
  const float* bv   = (const float*)d_in[10];
  const float* Wo   = (const float*)d_in[11];
  const float* bo   = (const float*)d_in[12];
  const float* centers = (const float*)d_in[13];
  const float* widths  = (const float*)d_in[14];
  const float* geom_w  = (const float*)d_in[15];
  const float* geom_b  = (const float*)d_in[16];
  const float* cq_w = (const float*)d_in[17];
  const float* cq_b = (const float*)d_in[18];
  const float* ck_w = (const float*)d_in[19];
  const float* ck_b = (const float*)d_in[20];
  const float* cv_w = (const float*)d_in[21];
  const float* cv_b = (const float*)d_in[22];
  const float* w1m  = (const float*)d_in[23];
  const float* b1m  = (const float*)d_in[24];
  const float* w2m  = (const float*)d_in[25];
  const float* b2m  = (const float*)d_in[26];
  const float* fw1  = (const float*)d_in[27];
  const float* fb1  = (const float*)d_in[28];
  const float* fw2  = (const float*)d_in[29];
  const float* fb2  = (const float*)d_in[30];
  const float* g1   = (const float*)d_in[31];
  const float* be1  = (const float*)d_in[32];
  const float* g2   = (const float*)d_in[33];
  const float* be2  = (const float*)d_in[34];

  float* ws = (float*)d_ws;
  float* sb = ws + 0;                                       // 64
  unsigned short* A_bfT = (unsigned short*)(ws + 64);       // 16*256 bf16 -> ends 2112
  float* M     = ws + 2112;     // 256*336 = 86016 -> ends 88128
  float* vbias = ws + 88128;    // 352 -> ends 88480
  unsigned short* MMTb = (unsigned short*)(ws + 88480);     // 336*256 bf16 = 43008 floats -> ends 131488
  float* vb2   = ws + 131488;   // 352 -> ends 131840
  unsigned short* CV1Tb = (unsigned short*)(ws + 131840);   // 256*320 bf16 = 40960 floats -> ends 172800
  float* cb1   = ws + 172800;   // 256 -> ends 173056
  unsigned short* W1t = (unsigned short*)(ws + 173056);     // 512*256 bf16 = 65536 floats -> ends 238592
  unsigned short* W2t = (unsigned short*)(ws + 238592);     // 256*512 bf16 = 65536 floats -> ends 304128
  unsigned short* W2mTb = (unsigned short*)(ws + 304128);   // 256*256 bf16 = 32768 floats -> ends 336896
  unsigned short* WvTb = (unsigned short*)(ws + 336896);    // 256*256 bf16 = 32768 floats -> ends 369664
  float* updw = ws + 369664;                                // 8192*256 f32 -> ends 2466816
  unsigned short* geomT = (unsigned short*)(ws + 2466816);  // 64*32 bf16
  // total ws use: ~10 MB

  // scratch inside d_out (134 MB, fully overwritten by kf at the end):
  float* outp = (float*)d_out;
  unsigned short* zbf = (unsigned short*)(outp + 21626880); // 8192*320 bf16 = 5.24 MB

  prepA<<<dim3(1867), dim3(352), 0, stream>>>(seed, Wq, bq, Wk, bk, A_bfT, sb,
      cq_w, cq_b, ck_w, ck_b, M, vbias,
      cv_w, cv_b, w1m, b1m, CV1Tb, cb1,
      fw1, fw2, w2m, geom_w, W1t, W2t, W2mTb, geomT, Wv, WvTb);
  kp2<<<dim3(257), dim3(352), 0, stream>>>(Wo, bo, M, vbias, MMTb, vb2);
  kgm3<<<dim3(2048), dim3(256), 0, stream>>>(x, pos, A_bfT, sb, WvTb, bv, MMTb, vb2,
      centers, widths, geomT, geom_b, zbf);
  gb2<<<dim3(512), dim3(256), 0, stream>>>(zbf, CV1Tb, cb1, W2mTb, b2m, updw);
  kf<<<dim3(2048), dim3(512), 0, stream>>>(x, updw, W1t, W2t, fb1, fb2, g1, be1, g2, be2, outp);
}